// Round 2
// baseline (2392.278 us; speedup 1.0000x reference)
//
#include <hip/hip_runtime.h>
#include <math.h>

#define B_   8
#define N_   3136
#define C_   256
#define NH_  8
#define HD_  32
#define LL_  9
#define PL_  49
#define HF_  682
#define HH   56
#define WW   56
#define MROWS (B_*N_)   // 25088

static __device__ __forceinline__ float gelu_f(float x){ return 0.5f*x*(1.0f+erff(x*0.70710678118654752f)); }
static __device__ __forceinline__ float rsum32(float v){
  #pragma unroll
  for (int m=16;m>0;m>>=1) v += __shfl_xor(v,m,32);
  return v;
}
static __device__ __forceinline__ float rsum64(float v){
  #pragma unroll
  for (int m=32;m>0;m>>=1) v += __shfl_xor(v,m,64);
  return v;
}
static __device__ __forceinline__ float rmax64(float v){
  #pragma unroll
  for (int m=32;m>0;m>>=1) v = fmaxf(v,__shfl_xor(v,m,64));
  return v;
}

// ---------------- LayerNorm over C=256, one block per row ----------------
__global__ __launch_bounds__(256) void ln_kernel(const float* __restrict__ in,
                                                 const float* __restrict__ w,
                                                 const float* __restrict__ bsh,
                                                 float* __restrict__ out){
  int row = blockIdx.x, tid = threadIdx.x;
  float v = in[(size_t)row*C_+tid];
  float s = rsum64(v), q = rsum64(v*v);
  __shared__ float s1[4], s2[4];
  if ((tid&63)==0){ s1[tid>>6]=s; s2[tid>>6]=q; }
  __syncthreads();
  float ts=s1[0]+s1[1]+s1[2]+s1[3];
  float tq=s2[0]+s2[1]+s2[2]+s2[3];
  float m = ts*(1.0f/C_);
  float var = tq*(1.0f/C_)-m*m;
  float inv = rsqrtf(var+1e-5f);
  out[(size_t)row*C_+tid] = (v-m)*inv*w[tid]+bsh[tid];
}

// ---------------- Generic tiled GEMM: out[M,Nt] = A[M,K] * W[Nt,K]^T + bias (+res, act) ----
template<int ACT, int RES>
__global__ __launch_bounds__(256) void gemm_kernel(const float* __restrict__ A,
                                                   const float* __restrict__ W,
                                                   const float* __restrict__ bias,
                                                   const float* __restrict__ res,
                                                   float* __restrict__ out,
                                                   int M, int Nt, int K){
  __shared__ float As[64][33];
  __shared__ float Bs[64][33];
  int m0 = blockIdx.x*64, n0 = blockIdx.y*64;
  int tid = threadIdx.x;
  int tx = tid & 15, ty = tid >> 4;
  float acc[4][4] = {{0.f}};
  int r  = tid >> 2;          // 0..63
  int cs = (tid & 3) * 8;     // 0,8,16,24
  for (int k0=0; k0<K; k0+=32){
    #pragma unroll
    for (int e=0;e<8;e++){
      int gc = k0+cs+e;
      float av = 0.f, bv = 0.f;
      if (gc < K){
        if (m0+r < M)  av = A[(size_t)(m0+r)*K + gc];
        if (n0+r < Nt) bv = W[(size_t)(n0+r)*K + gc];
      }
      As[r][cs+e] = av;
      Bs[r][cs+e] = bv;
    }
    __syncthreads();
    #pragma unroll 8
    for (int kk=0;kk<32;kk++){
      float a[4], b[4];
      #pragma unroll
      for (int i=0;i<4;i++) a[i] = As[ty*4+i][kk];
      #pragma unroll
      for (int j=0;j<4;j++) b[j] = Bs[tx*4+j][kk];
      #pragma unroll
      for (int i=0;i<4;i++)
        #pragma unroll
        for (int j=0;j<4;j++)
          acc[i][j] = fmaf(a[i], b[j], acc[i][j]);
    }
    __syncthreads();
  }
  #pragma unroll
  for (int i=0;i<4;i++){
    int gr = m0+ty*4+i;
    if (gr >= M) continue;
    #pragma unroll
    for (int j=0;j<4;j++){
      int gc = n0+tx*4+j;
      if (gc >= Nt) continue;
      float v = acc[i][j] + bias[gc];
      if (ACT==1) v = gelu_f(v);
      if (RES)   v += res[(size_t)gr*Nt+gc];
      out[(size_t)gr*Nt+gc] = v;
    }
  }
}

// ---------------- q post: per-head l2norm (in place) + q_scaled ----------------
__global__ __launch_bounds__(256) void qpost_kernel(float* __restrict__ q,
                                                    const float* __restrict__ qe,
                                                    const float* __restrict__ temp,
                                                    const float* __restrict__ sls,
                                                    float* __restrict__ qs_out){
  int row = blockIdx.x, tid = threadIdx.x, h = tid>>5;
  size_t idx = (size_t)row*C_ + tid;
  float v = q[idx];
  float ss = rsum32(v*v);
  float qn = v / fmaxf(sqrtf(ss), 1e-12f);
  q[idx] = qn;
  float t  = temp[h];
  float sp = log1pf(expf(t));
  float scale = sp * sls[0];
  qs_out[idx] = (qn + qe[tid])*scale;
}

// ---------------- k l2norm in place (first 256 of stride-512 rows) ----------------
__global__ __launch_bounds__(256) void knorm_kernel(float* __restrict__ kv){
  int row = blockIdx.x, tid = threadIdx.x;
  size_t idx = (size_t)row*512 + tid;
  float v = kv[idx];
  float ss = rsum32(v*v);
  kv[idx] = v / fmaxf(sqrtf(ss), 1e-12f);
}

// ---------------- 8x8 avg pool + LayerNorm(normp) ----------------
__global__ __launch_bounds__(256) void pool_ln_kernel(const float* __restrict__ xsr,
                                                      const float* __restrict__ w,
                                                      const float* __restrict__ bsh,
                                                      float* __restrict__ out){
  int blk = blockIdx.x; int b = blk/PL_; int p = blk%PL_;
  int py = p/7, px = p%7;
  int o = threadIdx.x;
  float s = 0.f;
  for (int iy=0;iy<8;iy++){
    const float* rowp = xsr + ((size_t)(b*N_ + (py*8+iy)*WW + px*8))*C_ + o;
    #pragma unroll
    for (int ix=0;ix<8;ix++) s += rowp[(size_t)ix*C_];
  }
  s *= (1.0f/64.0f);
  float su = rsum64(s), sq = rsum64(s*s);
  __shared__ float s1[4], s2[4];
  if ((o&63)==0){ s1[o>>6]=su; s2[o>>6]=sq; }
  __syncthreads();
  float ts=s1[0]+s1[1]+s1[2]+s1[3];
  float tq=s2[0]+s2[1]+s2[2]+s2[3];
  float m = ts*(1.0f/256.0f), var = tq*(1.0f/256.0f)-m*m;
  float inv = rsqrtf(var+1e-5f);
  out[(size_t)blk*C_+o] = (s-m)*inv*w[o]+bsh[o];
}

// ---------------- CPB MLP: cpb[t,h] ----------------
__global__ __launch_bounds__(256) void cpb_kernel(const float* __restrict__ rct,
                                                  const float* __restrict__ w1,
                                                  const float* __restrict__ b1,
                                                  const float* __restrict__ w2,
                                                  const float* __restrict__ b2v,
                                                  float* __restrict__ cpb){
  __shared__ float r[512];
  int t = blockIdx.x, tid = threadIdx.x;
  float c0 = rct[t*2], c1 = rct[t*2+1];
  for (int j=tid;j<512;j+=256){
    float v = c0*w1[j*2] + c1*w1[j*2+1] + b1[j];
    r[j] = fmaxf(v, 0.f);
  }
  __syncthreads();
  int h = tid>>5, lane = tid&31;
  float s = 0.f;
  for (int j=lane;j<512;j+=32) s += r[j]*w2[h*512+j];
  s = rsum32(s);
  if (lane==0) cpb[t*8+h] = s + b2v[h];
}

// ---------------- local window attention logits ----------------
__global__ __launch_bounds__(256) void attn_local_kernel(const float* __restrict__ qs,
                                                         const float* __restrict__ kv,
                                                         const float* __restrict__ rpb,
                                                         float* __restrict__ attn){
  int blk = blockIdx.x; int b = blk / N_; int n = blk % N_;
  int y = n / WW, x = n % WW;
  int tid = threadIdx.x, h = tid>>5, d = tid&31;
  float q = qs[(size_t)blk*C_ + tid];
  float* arow = attn + ((size_t)(b*NH_+h)*N_ + n)*58;
  #pragma unroll
  for (int l=0;l<9;l++){
    int yy = y + l/3 - 1, xx = x + l%3 - 1;
    float kval = 0.f;
    if (yy>=0 && yy<HH && xx>=0 && xx<WW)
      kval = kv[((size_t)(b*N_ + yy*WW + xx))*512 + tid];
    float s = rsum32(q*kval);
    if (d==0) arow[l] = s + rpb[h*9+l];
  }
}

// ---------------- pooled attention logits ----------------
__global__ __launch_bounds__(256) void attn_pool_kernel(const float* __restrict__ qs,
                                                        const float* __restrict__ kvp2,
                                                        const float* __restrict__ cpb,
                                                        const int* __restrict__ ridx,
                                                        float* __restrict__ attn){
  int blk = blockIdx.x; int b = blk / N_; int n = blk % N_;
  int tid = threadIdx.x, h = tid>>5, d = tid&31;
  float q = qs[(size_t)blk*C_ + tid];
  float* arow = attn + ((size_t)(b*NH_+h)*N_ + n)*58 + 9;
  const int* ir = ridx + (size_t)n*49;
  for (int p=0;p<49;p++){
    float kval = kvp2[((size_t)(b*PL_+p))*512 + tid];
    float s = rsum32(q*kval);
    if (d==0) arow[p] = s + cpb[ir[p]*8 + h];
  }
}

// ---------------- softmax over 58, one wave per row ----------------
__global__ __launch_bounds__(256) void softmax_kernel(float* __restrict__ attn){
  int row  = blockIdx.x*4 + (threadIdx.x>>6);
  int lane = threadIdx.x & 63;
  float* p = attn + (size_t)row*58;
  float v = (lane<58) ? p[lane] : -1e30f;
  float mx = rmax64(v);
  float e = (lane<58) ? expf(v-mx) : 0.f;
  float s = rsum64(e);
  if (lane<58) p[lane] = e/s;
}

// ---------------- x_local + x_pool -> out (B,N,C) ----------------
__global__ __launch_bounds__(256) void xout_kernel(const float* __restrict__ qn,
                                                   const float* __restrict__ lt,
                                                   const float* __restrict__ lb,
                                                   const float* __restrict__ attn,
                                                   const float* __restrict__ kv,
                                                   const float* __restrict__ kvp2,
                                                   float* __restrict__ out){
  int blk = blockIdx.x; int b = blk/N_; int n = blk%N_;
  int y = n/WW, x = n%WW;
  int tid = threadIdx.x, h = tid>>5, d = tid&31;
  float q = qn[(size_t)blk*C_+tid];
  const float* arow = attn + ((size_t)(b*NH_+h)*N_ + n)*58;
  float acc = 0.f;
  #pragma unroll
  for (int l=0;l<9;l++){
    float c = rsum32(q * lt[h*288 + d*9 + l]);
    c += lb[h*9+l] + arow[l];
    int yy=y+l/3-1, xx=x+l%3-1;
    float vv = 0.f;
    if (yy>=0 && yy<HH && xx>=0 && xx<WW)
      vv = kv[((size_t)(b*N_+yy*WW+xx))*512 + 256 + tid];
    acc += c*vv;
  }
  for (int p=0;p<49;p++){
    acc += arow[9+p] * kvp2[((size_t)(b*PL_+p))*512 + 256 + tid];
  }
  out[(size_t)blk*C_+tid] = acc;
}

// ---------------- depthwise 3x3 conv + gelu gate ----------------
__global__ __launch_bounds__(256) void dwconv_kernel(const float* __restrict__ h,
                                                     const float* __restrict__ dww,
                                                     const float* __restrict__ dwb,
                                                     float* __restrict__ hg){
  int blk = blockIdx.x; int b = blk/N_; int n = blk%N_;
  int y = n/WW, x = n%WW;
  for (int f=threadIdx.x; f<HF_; f+=256){
    float s = dwb[f];
    #pragma unroll
    for (int l=0;l<9;l++){
      int yy=y+l/3-1, xx=x+l%3-1;
      if (yy>=0 && yy<HH && xx>=0 && xx<WW)
        s += h[((size_t)(b*N_+yy*WW+xx))*1364 + f] * dww[f*9+l];
    }
    float g  = gelu_f(s);
    float vv = h[(size_t)blk*1364 + 682 + f];
    hg[(size_t)blk*682 + f] = g*vv;
  }
}

extern "C" void kernel_launch(void* const* d_in, const int* in_sizes, int n_in,
                              void* d_out, int out_size, void* d_ws, size_t ws_size,
                              hipStream_t stream) {
  const float* x    = (const float*)d_in[0];
  const float* rct  = (const float*)d_in[1];
  const float* sls  = (const float*)d_in[2];
  const float* n1w  = (const float*)d_in[3];
  const float* n1b  = (const float*)d_in[4];
  const float* q_w  = (const float*)d_in[5];
  const float* q_b  = (const float*)d_in[6];
  const float* kv_w = (const float*)d_in[7];
  const float* kv_b = (const float*)d_in[8];
  const float* temp = (const float*)d_in[9];
  const float* qe   = (const float*)d_in[10];
  const float* rpb  = (const float*)d_in[11];
  const float* lt   = (const float*)d_in[12];
  const float* lb   = (const float*)d_in[13];
  const float* sr_w = (const float*)d_in[14];
  const float* sr_b = (const float*)d_in[15];
  const float* npw  = (const float*)d_in[16];
  const float* npb  = (const float*)d_in[17];
  const float* c1w  = (const float*)d_in[18];
  const float* c1b  = (const float*)d_in[19];
  const float* c2w  = (const float*)d_in[20];
  const float* c2b  = (const float*)d_in[21];
  const float* pw   = (const float*)d_in[22];
  const float* pb   = (const float*)d_in[23];
  const float* n2w  = (const float*)d_in[24];
  const float* n2b  = (const float*)d_in[25];
  const float* f1w  = (const float*)d_in[26];
  const float* f1b  = (const float*)d_in[27];
  const float* dww  = (const float*)d_in[28];
  const float* dwb  = (const float*)d_in[29];
  const float* f2w  = (const float*)d_in[30];
  const float* f2bb = (const float*)d_in[31];
  const int*  ridx  = (const int*)d_in[32];
  float* outp = (float*)d_out;

  char* ws = (char*)d_ws;
  // All sizes are multiples of 256 bytes.
  constexpr size_t SZ_BNC  = (size_t)MROWS*C_*4;        // 25,690,112
  constexpr size_t SZ_KV   = (size_t)MROWS*512*4;       // 51,380,224
  constexpr size_t SZ_ATTN = (size_t)B_*NH_*N_*58*4;    // 46,563,328
  size_t o_xn   = 0;                                    // xn / xn2; hg overlays later
  size_t o_qn   = o_xn   + SZ_BNC;
  size_t o_qs   = o_qn   + SZ_BNC;
  size_t o_kv   = o_qs   + SZ_BNC;                      // kv; h overlays later (137MB, ends < o_x2)
  size_t o_attn = o_kv   + SZ_KV;
  size_t o_xsr  = o_attn + SZ_ATTN;
  size_t o_xpln = o_xsr  + SZ_BNC;
  size_t o_kvp2 = o_xpln + (size_t)B_*PL_*C_*4;
  size_t o_cpb  = o_kvp2 + (size_t)B_*PL_*512*4;
  size_t o_out  = o_cpb  + (size_t)1024*8*4;
  size_t o_x2   = o_out  + SZ_BNC;                      // ends at 253,321,216
  size_t o_h    = o_kv;   // 136.9MB over kv+attn+xsr+pool bufs+out region start (all dead); ends 213.9MB < o_x2 (227.6MB)
  size_t o_hg   = 0;      // 68.4MB over xn+qn+qs (dead after step 17)

  float* xn   = (float*)(ws + o_xn);
  float* qbuf = (float*)(ws + o_qn);    // raw q -> q_norm in place
  float* qsc  = (float*)(ws + o_qs);
  float* kv   = (float*)(ws + o_kv);
  float* attn = (float*)(ws + o_attn);
  float* xsr  = (float*)(ws + o_xsr);
  float* xpln = (float*)(ws + o_xpln);
  float* kvp2 = (float*)(ws + o_kvp2);
  float* cpb  = (float*)(ws + o_cpb);
  float* outb = (float*)(ws + o_out);
  float* x2   = (float*)(ws + o_x2);
  float* hbuf = (float*)(ws + o_h);
  float* hg   = (float*)(ws + o_hg);

  // 1. xn = LN(x)
  ln_kernel<<<MROWS, 256, 0, stream>>>(x, n1w, n1b, xn);
  // 2. q = xn @ q_w^T + q_b
  gemm_kernel<0,0><<<dim3(392,4), 256, 0, stream>>>(xn, q_w, q_b, nullptr, qbuf, MROWS, 256, 256);
  // 3. kv = xn @ kv_w^T + kv_b
  gemm_kernel<0,0><<<dim3(392,8), 256, 0, stream>>>(xn, kv_w, kv_b, nullptr, kv, MROWS, 512, 256);
  // 4. q_norm (in place) + q_scaled
  qpost_kernel<<<MROWS, 256, 0, stream>>>(qbuf, qe, temp, sls, qsc);
  // 5. k l2norm in place
  knorm_kernel<<<MROWS, 256, 0, stream>>>(kv);
  // 6. x_sr = gelu(xn @ sr_w^T + sr_b)
  gemm_kernel<1,0><<<dim3(392,4), 256, 0, stream>>>(xn, sr_w, sr_b, nullptr, xsr, MROWS, 256, 256);
  // 7. 8x8 avg pool + LN(normp)
  pool_ln_kernel<<<B_*PL_, 256, 0, stream>>>(xsr, npw, npb, xpln);
  // 8. kvp2 = xpln @ kv_w^T + kv_b
  gemm_kernel<0,0><<<dim3(7,8), 256, 0, stream>>>(xpln, kv_w, kv_b, nullptr, kvp2, B_*PL_, 512, 256);
  // 9. k_pool l2norm in place
  knorm_kernel<<<B_*PL_, 256, 0, stream>>>(kvp2);
  // 10. CPB MLP
  cpb_kernel<<<1024, 256, 0, stream>>>(rct, c1w, c1b, c2w, c2b, cpb);
  // 11. local attention logits
  attn_local_kernel<<<MROWS, 256, 0, stream>>>(qsc, kv, rpb, attn);
  // 12. pooled attention logits
  attn_pool_kernel<<<MROWS, 256, 0, stream>>>(qsc, kvp2, cpb, ridx, attn);
  // 13. softmax over 58
  softmax_kernel<<<(B_*NH_*N_)/4, 256, 0, stream>>>(attn);
  // 14. x_local + x_pool -> out
  xout_kernel<<<MROWS, 256, 0, stream>>>(qbuf, lt, lb, attn, kv, kvp2, outb);
  // 15. x2 = x + out @ proj_w^T + proj_b
  gemm_kernel<0,1><<<dim3(392,4), 256, 0, stream>>>(outb, pw, pb, x, x2, MROWS, 256, 256);
  // 16. xn2 = LN(x2)  (reuses xn buffer)
  ln_kernel<<<MROWS, 256, 0, stream>>>(x2, n2w, n2b, xn);
  // 17. h = xn2 @ fc1_w^T + fc1_b
  gemm_kernel<0,0><<<dim3(392,22), 256, 0, stream>>>(xn, f1w, f1b, nullptr, hbuf, MROWS, 1364, 256);
  // 18. hg = gelu(dwconv(h1)+dwb) * v
  dwconv_kernel<<<MROWS, 256, 0, stream>>>(hbuf, dww, dwb, hg);
  // 19. out = x2 + hg @ fc2_w^T + fc2_b
  gemm_kernel<0,1><<<dim3(392,4), 256, 0, stream>>>(hg, f2w, f2bb, x2, outp, MROWS, 256, 682);
}

// Round 3
// 1469.355 us; speedup vs baseline: 1.6281x; 1.6281x over previous
//
#include <hip/hip_runtime.h>
#include <math.h>

#define B_   8
#define N_   3136
#define C_   256
#define NH_  8
#define HD_  32
#define LL_  9
#define PL_  49
#define HF_  682
#define HH   56
#define WW   56
#define MROWS (B_*N_)   // 25088
#define HGLD  688       // padded row stride for hg (682 -> 688, 16B-aligned rows)

typedef short bf16x8 __attribute__((ext_vector_type(8)));
typedef float f32x4  __attribute__((ext_vector_type(4)));

static __device__ __forceinline__ float gelu_f(float x){ return 0.5f*x*(1.0f+erff(x*0.70710678118654752f)); }
static __device__ __forceinline__ unsigned short f2bf(float f){
  union { float f; unsigned u; } x; x.f = f;
  unsigned r = (x.u + 0x7FFFu + ((x.u >> 16) & 1u)) >> 16;
  return (unsigned short)r;
}
static __device__ __forceinline__ float rsum32(float v){
  #pragma unroll
  for (int m=16;m>0;m>>=1) v += __shfl_xor(v,m,32);
  return v;
}
static __device__ __forceinline__ float rsum64(float v){
  #pragma unroll
  for (int m=32;m>0;m>>=1) v += __shfl_xor(v,m,64);
  return v;
}
static __device__ __forceinline__ float rmax64(float v){
  #pragma unroll
  for (int m=32;m>0;m>>=1) v = fmaxf(v,__shfl_xor(v,m,64));
  return v;
}

// ---------------- LayerNorm over C=256, one block per row ----------------
__global__ __launch_bounds__(256) void ln_kernel(const float* __restrict__ in,
                                                 const float* __restrict__ w,
                                                 const float* __restrict__ bsh,
                                                 float* __restrict__ out){
  int row = blockIdx.x, tid = threadIdx.x;
  float v = in[(size_t)row*C_+tid];
  float s = rsum64(v), q = rsum64(v*v);
  __shared__ float s1[4], s2[4];
  if ((tid&63)==0){ s1[tid>>6]=s; s2[tid>>6]=q; }
  __syncthreads();
  float ts=s1[0]+s1[1]+s1[2]+s1[3];
  float tq=s2[0]+s2[1]+s2[2]+s2[3];
  float m = ts*(1.0f/C_);
  float var = tq*(1.0f/C_)-m*m;
  float inv = rsqrtf(var+1e-5f);
  out[(size_t)row*C_+tid] = (v-m)*inv*w[tid]+bsh[tid];
}

// ---------------- bf16 MFMA GEMM: out[M,Nt] = A[M,K](lda) * W[Nt,K]^T + bias (+res, act) ----
// 128x128 tile, BK=32, 4 waves of 64x64 (4x4 of 16x16x32 bf16 MFMA).
template<int ACT, int RES>
__global__ __launch_bounds__(256) void mfma_gemm(const float* __restrict__ A, int lda,
                                                 const float* __restrict__ W,
                                                 const float* __restrict__ bias,
                                                 const float* __restrict__ res,
                                                 float* __restrict__ out,
                                                 int M, int Nt, int K){
  constexpr int LDT = 40; // ushort stride per tile row (80B: 16B-aligned b128 frags, <=2-way bank alias)
  __shared__ unsigned short As[128*LDT];
  __shared__ unsigned short Bs[128*LDT];
  int tid = threadIdx.x, lane = tid & 63, wave = tid >> 6;
  int m0 = blockIdx.x*128, n0 = blockIdx.y*128;
  int wm = (wave>>1)*64, wn = (wave&1)*64;
  f32x4 acc[4][4];
  #pragma unroll
  for (int i=0;i<4;i++)
    #pragma unroll
    for (int j=0;j<4;j++) acc[i][j] = (f32x4){0.f,0.f,0.f,0.f};

  const bool w4 = ((K & 3) == 0);
  const int Kt = (K + 31) & ~31;
  const int l15 = lane & 15, quad = lane >> 4;

  for (int k0=0; k0<Kt; k0+=32){
    // ---- stage A tile (f32 -> bf16), 128x32 ----
    #pragma unroll
    for (int i=0;i<4;i++){
      int chunk = i*256 + tid;
      int r = chunk >> 3, c = (chunk & 7)*4;
      int gk = k0 + c, gr = m0 + r;
      float4 v = {0.f,0.f,0.f,0.f};
      if (gr < M){
        const float* ap = A + (size_t)gr*lda;
        if (gk + 4 <= K) v = *(const float4*)(ap + gk);
        else if (gk < K){
          v.x = ap[gk];
          if (gk+1 < K) v.y = ap[gk+1];
          if (gk+2 < K) v.z = ap[gk+2];
        }
      }
      ushort4 o; o.x=f2bf(v.x); o.y=f2bf(v.y); o.z=f2bf(v.z); o.w=f2bf(v.w);
      *(ushort4*)(&As[r*LDT + c]) = o;
    }
    // ---- stage W tile (f32 -> bf16), 128x32 ----
    if (w4){
      #pragma unroll
      for (int i=0;i<4;i++){
        int chunk = i*256 + tid;
        int r = chunk >> 3, c = (chunk & 7)*4;
        int gk = k0 + c, gn = n0 + r;
        float4 v = {0.f,0.f,0.f,0.f};
        if (gn < Nt){
          const float* wp = W + (size_t)gn*K;
          if (gk + 4 <= K) v = *(const float4*)(wp + gk);
          else if (gk < K){
            v.x = wp[gk];
            if (gk+1 < K) v.y = wp[gk+1];
            if (gk+2 < K) v.z = wp[gk+2];
          }
        }
        ushort4 o; o.x=f2bf(v.x); o.y=f2bf(v.y); o.z=f2bf(v.z); o.w=f2bf(v.w);
        *(ushort4*)(&Bs[r*LDT + c]) = o;
      }
    } else {
      #pragma unroll
      for (int i=0;i<8;i++){
        int chunk = i*256 + tid;
        int r = chunk >> 4, c = (chunk & 15)*2;
        int gk = k0 + c, gn = n0 + r;
        float2 v = {0.f,0.f};
        if (gn < Nt){
          const float* wp = W + (size_t)gn*K;
          if (gk + 2 <= K) v = *(const float2*)(wp + gk);
          else if (gk < K) v.x = wp[gk];
        }
        ushort2 o; o.x=f2bf(v.x); o.y=f2bf(v.y);
        *(ushort2*)(&Bs[r*LDT + c]) = o;
      }
    }
    __syncthreads();
    // ---- fragments + MFMA ----
    bf16x8 af[4], bfr[4];
    #pragma unroll
    for (int mi=0;mi<4;mi++)
      af[mi] = *(bf16x8*)(&As[(wm + mi*16 + l15)*LDT + quad*8]);
    #pragma unroll
    for (int nj=0;nj<4;nj++)
      bfr[nj] = *(bf16x8*)(&Bs[(wn + nj*16 + l15)*LDT + quad*8]);
    #pragma unroll
    for (int mi=0;mi<4;mi++)
      #pragma unroll
      for (int nj=0;nj<4;nj++)
        acc[mi][nj] = __builtin_amdgcn_mfma_f32_16x16x32_bf16(af[mi], bfr[nj], acc[mi][nj], 0,0,0);
    __syncthreads();
  }
  // ---- epilogue: C/D layout col=lane&15, row=quad*4+reg ----
  int rbase = quad*4;
  #pragma unroll
  for (int nj=0;nj<4;nj++){
    int gc = n0 + wn + nj*16 + l15;
    if (gc >= Nt) continue;
    float bv = bias[gc];
    #pragma unroll
    for (int mi=0;mi<4;mi++){
      #pragma unroll
      for (int reg=0;reg<4;reg++){
        int gr = m0 + wm + mi*16 + rbase + reg;
        if (gr >= M) continue;
        float v = acc[mi][nj][reg] + bv;
        if (ACT==1) v = gelu_f(v);
        if (RES)   v += res[(size_t)gr*Nt + gc];
        out[(size_t)gr*Nt + gc] = v;
      }
    }
  }
}

// ---------------- q post: per-head l2norm (in place) + q_scaled ----------------
__global__ __launch_bounds__(256) void qpost_kernel(float* __restrict__ q,
                                                    const float* __restrict__ qe,
                                                    const float* __restrict__ temp,
                                                    const float* __restrict__ sls,
                                                    float* __restrict__ qs_out){
  int row = blockIdx.x, tid = threadIdx.x, h = tid>>5;
  size_t idx = (size_t)row*C_ + tid;
  float v = q[idx];
  float ss = rsum32(v*v);
  float qn = v / fmaxf(sqrtf(ss), 1e-12f);
  q[idx] = qn;
  float t  = temp[h];
  float sp = log1pf(expf(t));
  float scale = sp * sls[0];
  qs_out[idx] = (qn + qe[tid])*scale;
}

// ---------------- k l2norm in place (first 256 of stride-512 rows) ----------------
__global__ __launch_bounds__(256) void knorm_kernel(float* __restrict__ kv){
  int row = blockIdx.x, tid = threadIdx.x;
  size_t idx = (size_t)row*512 + tid;
  float v = kv[idx];
  float ss = rsum32(v*v);
  kv[idx] = v / fmaxf(sqrtf(ss), 1e-12f);
}

// ---------------- 8x8 avg pool + LayerNorm(normp) ----------------
__global__ __launch_bounds__(256) void pool_ln_kernel(const float* __restrict__ xsr,
                                                      const float* __restrict__ w,
                                                      const float* __restrict__ bsh,
                                                      float* __restrict__ out){
  int blk = blockIdx.x; int b = blk/PL_; int p = blk%PL_;
  int py = p/7, px = p%7;
  int o = threadIdx.x;
  float s = 0.f;
  for (int iy=0;iy<8;iy++){
    const float* rowp = xsr + ((size_t)(b*N_ + (py*8+iy)*WW + px*8))*C_ + o;
    #pragma unroll
    for (int ix=0;ix<8;ix++) s += rowp[(size_t)ix*C_];
  }
  s *= (1.0f/64.0f);
  float su = rsum64(s), sq = rsum64(s*s);
  __shared__ float s1[4], s2[4];
  if ((o&63)==0){ s1[o>>6]=su; s2[o>>6]=sq; }
  __syncthreads();
  float ts=s1[0]+s1[1]+s1[2]+s1[3];
  float tq=s2[0]+s2[1]+s2[2]+s2[3];
  float m = ts*(1.0f/256.0f), var = tq*(1.0f/256.0f)-m*m;
  float inv = rsqrtf(var+1e-5f);
  out[(size_t)blk*C_+o] = (s-m)*inv*w[o]+bsh[o];
}

// ---------------- CPB MLP: cpb[t,h] ----------------
__global__ __launch_bounds__(256) void cpb_kernel(const float* __restrict__ rct,
                                                  const float* __restrict__ w1,
                                                  const float* __restrict__ b1,
                                                  const float* __restrict__ w2,
                                                  const float* __restrict__ b2v,
                                                  float* __restrict__ cpb){
  __shared__ float r[512];
  int t = blockIdx.x, tid = threadIdx.x;
  float c0 = rct[t*2], c1 = rct[t*2+1];
  for (int j=tid;j<512;j+=256){
    float v = c0*w1[j*2] + c1*w1[j*2+1] + b1[j];
    r[j] = fmaxf(v, 0.f);
  }
  __syncthreads();
  int h = tid>>5, lane = tid&31;
  float s = 0.f;
  for (int j=lane;j<512;j+=32) s += r[j]*w2[h*512+j];
  s = rsum32(s);
  if (lane==0) cpb[t*8+h] = s + b2v[h];
}

// ---------------- local window attention logits ----------------
__global__ __launch_bounds__(256) void attn_local_kernel(const float* __restrict__ qs,
                                                         const float* __restrict__ kv,
                                                         const float* __restrict__ rpb,
                                                         float* __restrict__ attn){
  int blk = blockIdx.x; int b = blk / N_; int n = blk % N_;
  int y = n / WW, x = n % WW;
  int tid = threadIdx.x, h = tid>>5, d = tid&31;
  float q = qs[(size_t)blk*C_ + tid];
  float* arow = attn + ((size_t)(b*NH_+h)*N_ + n)*58;
  #pragma unroll
  for (int l=0;l<9;l++){
    int yy = y + l/3 - 1, xx = x + l%3 - 1;
    float kval = 0.f;
    if (yy>=0 && yy<HH && xx>=0 && xx<WW)
      kval = kv[((size_t)(b*N_ + yy*WW + xx))*512 + tid];
    float s = rsum32(q*kval);
    if (d==0) arow[l] = s + rpb[h*9+l];
  }
}

// ---------------- pooled attention logits ----------------
__global__ __launch_bounds__(256) void attn_pool_kernel(const float* __restrict__ qs,
                                                        const float* __restrict__ kvp2,
                                                        const float* __restrict__ cpb,
                                                        const int* __restrict__ ridx,
                                                        float* __restrict__ attn){
  int blk = blockIdx.x; int b = blk / N_; int n = blk % N_;
  int tid = threadIdx.x, h = tid>>5, d = tid&31;
  float q = qs[(size_t)blk*C_ + tid];
  float* arow = attn + ((size_t)(b*NH_+h)*N_ + n)*58 + 9;
  const int* ir = ridx + (size_t)n*49;
  for (int p=0;p<49;p++){
    float kval = kvp2[((size_t)(b*PL_+p))*512 + tid];
    float s = rsum32(q*kval);
    if (d==0) arow[p] = s + cpb[ir[p]*8 + h];
  }
}

// ---------------- softmax over 58, one wave per row ----------------
__global__ __launch_bounds__(256) void softmax_kernel(float* __restrict__ attn){
  int row  = blockIdx.x*4 + (threadIdx.x>>6);
  int lane = threadIdx.x & 63;
  float* p = attn + (size_t)row*58;
  float v = (lane<58) ? p[lane] : -1e30f;
  float mx = rmax64(v);
  float e = (lane<58) ? expf(v-mx) : 0.f;
  float s = rsum64(e);
  if (lane<58) p[lane] = e/s;
}

// ---------------- x_local + x_pool -> out (B,N,C) ----------------
__global__ __launch_bounds__(256) void xout_kernel(const float* __restrict__ qn,
                                                   const float* __restrict__ lt,
                                                   const float* __restrict__ lb,
                                                   const float* __restrict__ attn,
                                                   const float* __restrict__ kv,
                                                   const float* __restrict__ kvp2,
                                                   float* __restrict__ out){
  int blk = blockIdx.x; int b = blk/N_; int n = blk%N_;
  int y = n/WW, x = n%WW;
  int tid = threadIdx.x, h = tid>>5, d = tid&31;
  float q = qn[(size_t)blk*C_+tid];
  const float* arow = attn + ((size_t)(b*NH_+h)*N_ + n)*58;
  float acc = 0.f;
  #pragma unroll
  for (int l=0;l<9;l++){
    float c = rsum32(q * lt[h*288 + d*9 + l]);
    c += lb[h*9+l] + arow[l];
    int yy=y+l/3-1, xx=x+l%3-1;
    float vv = 0.f;
    if (yy>=0 && yy<HH && xx>=0 && xx<WW)
      vv = kv[((size_t)(b*N_+yy*WW+xx))*512 + 256 + tid];
    acc += c*vv;
  }
  for (int p=0;p<49;p++){
    acc += arow[9+p] * kvp2[((size_t)(b*PL_+p))*512 + 256 + tid];
  }
  out[(size_t)blk*C_+tid] = acc;
}

// ---------------- depthwise 3x3 conv + gelu gate (hg has padded stride HGLD) ----------------
__global__ __launch_bounds__(256) void dwconv_kernel(const float* __restrict__ h,
                                                     const float* __restrict__ dww,
                                                     const float* __restrict__ dwb,
                                                     float* __restrict__ hg){
  int blk = blockIdx.x; int b = blk/N_; int n = blk%N_;
  int y = n/WW, x = n%WW;
  for (int f=threadIdx.x; f<HF_; f+=256){
    float s = dwb[f];
    #pragma unroll
    for (int l=0;l<9;l++){
      int yy=y+l/3-1, xx=x+l%3-1;
      if (yy>=0 && yy<HH && xx>=0 && xx<WW)
        s += h[((size_t)(b*N_+yy*WW+xx))*1364 + f] * dww[f*9+l];
    }
    float g  = gelu_f(s);
    float vv = h[(size_t)blk*1364 + 682 + f];
    hg[(size_t)blk*HGLD + f] = g*vv;
  }
}

extern "C" void kernel_launch(void* const* d_in, const int* in_sizes, int n_in,
                              void* d_out, int out_size, void* d_ws, size_t ws_size,
                              hipStream_t stream) {
  const float* x    = (const float*)d_in[0];
  const float* rct  = (const float*)d_in[1];
  const float* sls  = (const float*)d_in[2];
  const float* n1w  = (const float*)d_in[3];
  const float* n1b  = (const float*)d_in[4];
  const float* q_w  = (const float*)d_in[5];
  const float* q_b  = (const float*)d_in[6];
  const float* kv_w = (const float*)d_in[7];
  const float* kv_b = (const float*)d_in[8];
  const float* temp = (const float*)d_in[9];
  const float* qe   = (const float*)d_in[10];
  const float* rpb  = (const float*)d_in[11];
  const float* lt   = (const float*)d_in[12];
  const float* lb   = (const float*)d_in[13];
  const float* sr_w = (const float*)d_in[14];
  const float* sr_b = (const float*)d_in[15];
  const float* npw  = (const float*)d_in[16];
  const float* npb  = (const float*)d_in[17];
  const float* c1w  = (const float*)d_in[18];
  const float* c1b  = (const float*)d_in[19];
  const float* c2w  = (const float*)d_in[20];
  const float* c2b  = (const float*)d_in[21];
  const float* pw   = (const float*)d_in[22];
  const float* pb   = (const float*)d_in[23];
  const float* n2w  = (const float*)d_in[24];
  const float* n2b  = (const float*)d_in[25];
  const float* f1w  = (const float*)d_in[26];
  const float* f1b  = (const float*)d_in[27];
  const float* dww  = (const float*)d_in[28];
  const float* dwb  = (const float*)d_in[29];
  const float* f2w  = (const float*)d_in[30];
  const float* f2bb = (const float*)d_in[31];
  const int*  ridx  = (const int*)d_in[32];
  float* outp = (float*)d_out;

  char* ws = (char*)d_ws;
  constexpr size_t SZ_BNC  = (size_t)MROWS*C_*4;        // 25,690,112
  constexpr size_t SZ_KV   = (size_t)MROWS*512*4;       // 51,380,224
  constexpr size_t SZ_ATTN = (size_t)B_*NH_*N_*58*4;    // 46,563,328
  size_t o_xn   = 0;
  size_t o_qn   = o_xn   + SZ_BNC;
  size_t o_qs   = o_qn   + SZ_BNC;
  size_t o_kv   = o_qs   + SZ_BNC;
  size_t o_attn = o_kv   + SZ_KV;
  size_t o_xsr  = o_attn + SZ_ATTN;
  size_t o_xpln = o_xsr  + SZ_BNC;
  size_t o_kvp2 = o_xpln + (size_t)B_*PL_*C_*4;
  size_t o_cpb  = o_kvp2 + (size_t)B_*PL_*512*4;
  size_t o_out  = o_cpb  + (size_t)1024*8*4;
  size_t o_x2   = o_out  + SZ_BNC;
  size_t o_h    = o_kv;   // 136.9MB over kv..outb (dead); ends < o_x2
  size_t o_hg   = 0;      // hg 25088*688*4 = 69.0MB over xn+qn+qs (77.1MB, dead after step 17)

  float* xn   = (float*)(ws + o_xn);
  float* qbuf = (float*)(ws + o_qn);
  float* qsc  = (float*)(ws + o_qs);
  float* kv   = (float*)(ws + o_kv);
  float* attn = (float*)(ws + o_attn);
  float* xsr  = (float*)(ws + o_xsr);
  float* xpln = (float*)(ws + o_xpln);
  float* kvp2 = (float*)(ws + o_kvp2);
  float* cpb  = (float*)(ws + o_cpb);
  float* outb = (float*)(ws + o_out);
  float* x2   = (float*)(ws + o_x2);
  float* hbuf = (float*)(ws + o_h);
  float* hg   = (float*)(ws + o_hg);

  // 1. xn = LN(x)
  ln_kernel<<<MROWS, 256, 0, stream>>>(x, n1w, n1b, xn);
  // 2. q = xn @ q_w^T + q_b
  mfma_gemm<0,0><<<dim3(196,2), 256, 0, stream>>>(xn, C_, q_w, q_b, nullptr, qbuf, MROWS, 256, 256);
  // 3. kv = xn @ kv_w^T + kv_b
  mfma_gemm<0,0><<<dim3(196,4), 256, 0, stream>>>(xn, C_, kv_w, kv_b, nullptr, kv, MROWS, 512, 256);
  // 4. q_norm (in place) + q_scaled
  qpost_kernel<<<MROWS, 256, 0, stream>>>(qbuf, qe, temp, sls, qsc);
  // 5. k l2norm in place
  knorm_kernel<<<MROWS, 256, 0, stream>>>(kv);
  // 6. x_sr = gelu(xn @ sr_w^T + sr_b)
  mfma_gemm<1,0><<<dim3(196,2), 256, 0, stream>>>(xn, C_, sr_w, sr_b, nullptr, xsr, MROWS, 256, 256);
  // 7. 8x8 avg pool + LN(normp)
  pool_ln_kernel<<<B_*PL_, 256, 0, stream>>>(xsr, npw, npb, xpln);
  // 8. kvp2 = xpln @ kv_w^T + kv_b
  mfma_gemm<0,0><<<dim3(4,4), 256, 0, stream>>>(xpln, C_, kv_w, kv_b, nullptr, kvp2, B_*PL_, 512, 256);
  // 9. k_pool l2norm in place
  knorm_kernel<<<B_*PL_, 256, 0, stream>>>(kvp2);
  // 10. CPB MLP
  cpb_kernel<<<1024, 256, 0, stream>>>(rct, c1w, c1b, c2w, c2b, cpb);
  // 11. local attention logits
  attn_local_kernel<<<MROWS, 256, 0, stream>>>(qsc, kv, rpb, attn);
  // 12. pooled attention logits
  attn_pool_kernel<<<MROWS, 256, 0, stream>>>(qsc, kvp2, cpb, ridx, attn);
  // 13. softmax over 58
  softmax_kernel<<<(B_*NH_*N_)/4, 256, 0, stream>>>(attn);
  // 14. x_local + x_pool -> out
  xout_kernel<<<MROWS, 256, 0, stream>>>(qbuf, lt, lb, attn, kv, kvp2, outb);
  // 15. x2 = x + out @ proj_w^T + proj_b
  mfma_gemm<0,1><<<dim3(196,2), 256, 0, stream>>>(outb, C_, pw, pb, x, x2, MROWS, 256, 256);
  // 16. xn2 = LN(x2)  (reuses xn buffer)
  ln_kernel<<<MROWS, 256, 0, stream>>>(x2, n2w, n2b, xn);
  // 17. h = xn2 @ fc1_w^T + fc1_b
  mfma_gemm<0,0><<<dim3(196,11), 256, 0, stream>>>(xn, C_, f1w, f1b, nullptr, hbuf, MROWS, 1364, 256);
  // 18. hg = gelu(dwconv(h1)+dwb) * v   (hg stride HGLD)
  dwconv_kernel<<<MROWS, 256, 0, stream>>>(hbuf, dww, dwb, hg);
  // 19. out = x2 + hg @ fc2_w^T + fc2_b  (A stride 688, K=682)
  mfma_gemm<0,1><<<dim3(196,2), 256, 0, stream>>>(hg, HGLD, f2w, f2bb, x2, outp, MROWS, 256, 682);
}

// Round 4
// 1135.957 us; speedup vs baseline: 2.1060x; 1.2935x over previous
//
#include <hip/hip_runtime.h>
#include <math.h>

#define B_   8
#define N_   3136
#define C_   256
#define NH_  8
#define HD_  32
#define LL_  9
#define PL_  49
#define HF_  682
#define HH   56
#define WW   56
#define MROWS (B_*N_)   // 25088
#define HGLD  688       // padded row stride for hg

typedef short bf16x8 __attribute__((ext_vector_type(8)));
typedef float f32x4  __attribute__((ext_vector_type(4)));

static __device__ __forceinline__ float gelu_f(float x){ return 0.5f*x*(1.0f+erff(x*0.70710678118654752f)); }
static __device__ __forceinline__ unsigned short f2bf(float f){
  union { float f; unsigned u; } x; x.f = f;
  unsigned r = (x.u + 0x7FFFu + ((x.u >> 16) & 1u)) >> 16;
  return (unsigned short)r;
}
static __device__ __forceinline__ float rsum32(float v){
  #pragma unroll
  for (int m=16;m>0;m>>=1) v += __shfl_xor(v,m,32);
  return v;
}
static __device__ __forceinline__ float rsum64(float v){
  #pragma unroll
  for (int m=32;m>0;m>>=1) v += __shfl_xor(v,m,64);
  return v;
}
static __device__ __forceinline__ float rmax64(float v){
  #pragma unroll
  for (int m=32;m>0;m>>=1) v = fmaxf(v,__shfl_xor(v,m,64));
  return v;
}

// ---------------- LayerNorm over C=256, one block per row ----------------
__global__ __launch_bounds__(256) void ln_kernel(const float* __restrict__ in,
                                                 const float* __restrict__ w,
                                                 const float* __restrict__ bsh,
                                                 float* __restrict__ out){
  int row = blockIdx.x, tid = threadIdx.x;
  float v = in[(size_t)row*C_+tid];
  float s = rsum64(v), q = rsum64(v*v);
  __shared__ float s1[4], s2[4];
  if ((tid&63)==0){ s1[tid>>6]=s; s2[tid>>6]=q; }
  __syncthreads();
  float ts=s1[0]+s1[1]+s1[2]+s1[3];
  float tq=s2[0]+s2[1]+s2[2]+s2[3];
  float m = ts*(1.0f/C_);
  float var = tq*(1.0f/C_)-m*m;
  float inv = rsqrtf(var+1e-5f);
  out[(size_t)row*C_+tid] = (v-m)*inv*w[tid]+bsh[tid];
}

// ---------------- bf16 MFMA GEMM (128x128 tile, BK=32) ----------------
template<int ACT, int RES>
__global__ __launch_bounds__(256) void mfma_gemm(const float* __restrict__ A, int lda,
                                                 const float* __restrict__ W,
                                                 const float* __restrict__ bias,
                                                 const float* __restrict__ res,
                                                 float* __restrict__ out,
                                                 int M, int Nt, int K){
  constexpr int LDT = 40;
  __shared__ unsigned short As[128*LDT];
  __shared__ unsigned short Bs[128*LDT];
  int tid = threadIdx.x, lane = tid & 63, wave = tid >> 6;
  int m0 = blockIdx.x*128, n0 = blockIdx.y*128;
  int wm = (wave>>1)*64, wn = (wave&1)*64;
  f32x4 acc[4][4];
  #pragma unroll
  for (int i=0;i<4;i++)
    #pragma unroll
    for (int j=0;j<4;j++) acc[i][j] = (f32x4){0.f,0.f,0.f,0.f};

  const bool w4 = ((K & 3) == 0);
  const int Kt = (K + 31) & ~31;
  const int l15 = lane & 15, quad = lane >> 4;

  for (int k0=0; k0<Kt; k0+=32){
    #pragma unroll
    for (int i=0;i<4;i++){
      int chunk = i*256 + tid;
      int r = chunk >> 3, c = (chunk & 7)*4;
      int gk = k0 + c, gr = m0 + r;
      float4 v = {0.f,0.f,0.f,0.f};
      if (gr < M){
        const float* ap = A + (size_t)gr*lda;
        if (gk + 4 <= K) v = *(const float4*)(ap + gk);
        else if (gk < K){
          v.x = ap[gk];
          if (gk+1 < K) v.y = ap[gk+1];
          if (gk+2 < K) v.z = ap[gk+2];
        }
      }
      ushort4 o; o.x=f2bf(v.x); o.y=f2bf(v.y); o.z=f2bf(v.z); o.w=f2bf(v.w);
      *(ushort4*)(&As[r*LDT + c]) = o;
    }
    if (w4){
      #pragma unroll
      for (int i=0;i<4;i++){
        int chunk = i*256 + tid;
        int r = chunk >> 3, c = (chunk & 7)*4;
        int gk = k0 + c, gn = n0 + r;
        float4 v = {0.f,0.f,0.f,0.f};
        if (gn < Nt){
          const float* wp = W + (size_t)gn*K;
          if (gk + 4 <= K) v = *(const float4*)(wp + gk);
          else if (gk < K){
            v.x = wp[gk];
            if (gk+1 < K) v.y = wp[gk+1];
            if (gk+2 < K) v.z = wp[gk+2];
          }
        }
        ushort4 o; o.x=f2bf(v.x); o.y=f2bf(v.y); o.z=f2bf(v.z); o.w=f2bf(v.w);
        *(ushort4*)(&Bs[r*LDT + c]) = o;
      }
    } else {
      #pragma unroll
      for (int i=0;i<8;i++){
        int chunk = i*256 + tid;
        int r = chunk >> 4, c = (chunk & 15)*2;
        int gk = k0 + c, gn = n0 + r;
        float2 v = {0.f,0.f};
        if (gn < Nt){
          const float* wp = W + (size_t)gn*K;
          if (gk + 2 <= K) v = *(const float2*)(wp + gk);
          else if (gk < K) v.x = wp[gk];
        }
        ushort2 o; o.x=f2bf(v.x); o.y=f2bf(v.y);
        *(ushort2*)(&Bs[r*LDT + c]) = o;
      }
    }
    __syncthreads();
    bf16x8 af[4], bfr[4];
    #pragma unroll
    for (int mi=0;mi<4;mi++)
      af[mi] = *(bf16x8*)(&As[(wm + mi*16 + l15)*LDT + quad*8]);
    #pragma unroll
    for (int nj=0;nj<4;nj++)
      bfr[nj] = *(bf16x8*)(&Bs[(wn + nj*16 + l15)*LDT + quad*8]);
    #pragma unroll
    for (int mi=0;mi<4;mi++)
      #pragma unroll
      for (int nj=0;nj<4;nj++)
        acc[mi][nj] = __builtin_amdgcn_mfma_f32_16x16x32_bf16(af[mi], bfr[nj], acc[mi][nj], 0,0,0);
    __syncthreads();
  }
  int rbase = quad*4;
  #pragma unroll
  for (int nj=0;nj<4;nj++){
    int gc = n0 + wn + nj*16 + l15;
    if (gc >= Nt) continue;
    float bv = bias[gc];
    #pragma unroll
    for (int mi=0;mi<4;mi++){
      #pragma unroll
      for (int reg=0;reg<4;reg++){
        int gr = m0 + wm + mi*16 + rbase + reg;
        if (gr >= M) continue;
        float v = acc[mi][nj][reg] + bv;
        if (ACT==1) v = gelu_f(v);
        if (RES)   v += res[(size_t)gr*Nt + gc];
        out[(size_t)gr*Nt + gc] = v;
      }
    }
  }
}

// ---------------- q post ----------------
__global__ __launch_bounds__(256) void qpost_kernel(float* __restrict__ q,
                                                    const float* __restrict__ qe,
                                                    const float* __restrict__ temp,
                                                    const float* __restrict__ sls,
                                                    float* __restrict__ qs_out){
  int row = blockIdx.x, tid = threadIdx.x, h = tid>>5;
  size_t idx = (size_t)row*C_ + tid;
  float v = q[idx];
  float ss = rsum32(v*v);
  float qn = v / fmaxf(sqrtf(ss), 1e-12f);
  q[idx] = qn;
  float t  = temp[h];
  float sp = log1pf(expf(t));
  float scale = sp * sls[0];
  qs_out[idx] = (qn + qe[tid])*scale;
}

// ---------------- k l2norm in place ----------------
__global__ __launch_bounds__(256) void knorm_kernel(float* __restrict__ kv){
  int row = blockIdx.x, tid = threadIdx.x;
  size_t idx = (size_t)row*512 + tid;
  float v = kv[idx];
  float ss = rsum32(v*v);
  kv[idx] = v / fmaxf(sqrtf(ss), 1e-12f);
}

// ---------------- 8x8 avg pool + LN ----------------
__global__ __launch_bounds__(256) void pool_ln_kernel(const float* __restrict__ xsr,
                                                      const float* __restrict__ w,
                                                      const float* __restrict__ bsh,
                                                      float* __restrict__ out){
  int blk = blockIdx.x; int b = blk/PL_; int p = blk%PL_;
  int py = p/7, px = p%7;
  int o = threadIdx.x;
  float s = 0.f;
  for (int iy=0;iy<8;iy++){
    const float* rowp = xsr + ((size_t)(b*N_ + (py*8+iy)*WW + px*8))*C_ + o;
    #pragma unroll
    for (int ix=0;ix<8;ix++) s += rowp[(size_t)ix*C_];
  }
  s *= (1.0f/64.0f);
  float su = rsum64(s), sq = rsum64(s*s);
  __shared__ float s1[4], s2[4];
  if ((o&63)==0){ s1[o>>6]=su; s2[o>>6]=sq; }
  __syncthreads();
  float ts=s1[0]+s1[1]+s1[2]+s1[3];
  float tq=s2[0]+s2[1]+s2[2]+s2[3];
  float m = ts*(1.0f/256.0f), var = tq*(1.0f/256.0f)-m*m;
  float inv = rsqrtf(var+1e-5f);
  out[(size_t)blk*C_+o] = (s-m)*inv*w[o]+bsh[o];
}

// ---------------- CPB MLP ----------------
__global__ __launch_bounds__(256) void cpb_kernel(const float* __restrict__ rct,
                                                  const float* __restrict__ w1,
                                                  const float* __restrict__ b1,
                                                  const float* __restrict__ w2,
                                                  const float* __restrict__ b2v,
                                                  float* __restrict__ cpb){
  __shared__ float r[512];
  int t = blockIdx.x, tid = threadIdx.x;
  float c0 = rct[t*2], c1 = rct[t*2+1];
  for (int j=tid;j<512;j+=256){
    float v = c0*w1[j*2] + c1*w1[j*2+1] + b1[j];
    r[j] = fmaxf(v, 0.f);
  }
  __syncthreads();
  int h = tid>>5, lane = tid&31;
  float s = 0.f;
  for (int j=lane;j<512;j+=32) s += r[j]*w2[h*512+j];
  s = rsum32(s);
  if (lane==0) cpb[t*8+h] = s + b2v[h];
}

// ---------------- local window attention logits ----------------
__global__ __launch_bounds__(256) void attn_local_kernel(const float* __restrict__ qs,
                                                         const float* __restrict__ kv,
                                                         const float* __restrict__ rpb,
                                                         float* __restrict__ attn){
  int blk = blockIdx.x; int b = blk / N_; int n = blk % N_;
  int y = n / WW, x = n % WW;
  int tid = threadIdx.x, h = tid>>5, d = tid&31;
  float q = qs[(size_t)blk*C_ + tid];
  float* arow = attn + ((size_t)(b*NH_+h)*N_ + n)*58;
  #pragma unroll
  for (int l=0;l<9;l++){
    int yy = y + l/3 - 1, xx = x + l%3 - 1;
    float kval = 0.f;
    if (yy>=0 && yy<HH && xx>=0 && xx<WW)
      kval = kv[((size_t)(b*N_ + yy*WW + xx))*512 + tid];
    float s = rsum32(q*kval);
    if (d==0) arow[l] = s + rpb[h*9+l];
  }
}

// ---------------- pooled attention logits via MFMA ----------------
// grid (49, 64): blockIdx.x = 64-row band, blockIdx.y = b*8+h. Wave = 16 rows x 49 p.
__global__ __launch_bounds__(256) void attn_pool_mfma(const float* __restrict__ qs,
                                                      const float* __restrict__ kvp2,
                                                      const float* __restrict__ cpb,
                                                      const int* __restrict__ ridx,
                                                      float* __restrict__ attn){
  int tid = threadIdx.x, lane = tid & 63, wave = tid >> 6;
  int l15 = lane & 15, quad = lane >> 4;
  int bh = blockIdx.y, b = bh >> 3, h = bh & 7;
  int n0 = (blockIdx.x*4 + wave)*16;
  // A fragment: Q rows n0+l15, k = quad*8 + j
  const float* qp = qs + ((size_t)(b*N_ + n0 + l15)*C_ + h*32 + quad*8);
  float4 a0 = *(const float4*)qp, a1 = *(const float4*)(qp+4);
  bf16x8 af;
  af[0]=(short)f2bf(a0.x); af[1]=(short)f2bf(a0.y); af[2]=(short)f2bf(a0.z); af[3]=(short)f2bf(a0.w);
  af[4]=(short)f2bf(a1.x); af[5]=(short)f2bf(a1.y); af[6]=(short)f2bf(a1.z); af[7]=(short)f2bf(a1.w);
  f32x4 acc[4];
  #pragma unroll
  for (int nj=0;nj<4;nj++){
    int p = nj*16 + l15;
    bf16x8 bfr = (bf16x8){0,0,0,0,0,0,0,0};
    if (p < PL_){
      const float* kp = kvp2 + ((size_t)(b*PL_ + p)*512 + h*32 + quad*8);
      float4 b0 = *(const float4*)kp, b1 = *(const float4*)(kp+4);
      bfr[0]=(short)f2bf(b0.x); bfr[1]=(short)f2bf(b0.y); bfr[2]=(short)f2bf(b0.z); bfr[3]=(short)f2bf(b0.w);
      bfr[4]=(short)f2bf(b1.x); bfr[5]=(short)f2bf(b1.y); bfr[6]=(short)f2bf(b1.z); bfr[7]=(short)f2bf(b1.w);
    }
    f32x4 z = (f32x4){0.f,0.f,0.f,0.f};
    acc[nj] = __builtin_amdgcn_mfma_f32_16x16x32_bf16(af, bfr, z, 0,0,0);
  }
  // epilogue: col(p) = nj*16+l15, row(n) = n0 + quad*4 + reg
  #pragma unroll
  for (int nj=0;nj<4;nj++){
    int p = nj*16 + l15;
    if (p >= PL_) continue;
    #pragma unroll
    for (int reg=0;reg<4;reg++){
      int n = n0 + quad*4 + reg;
      float bias = cpb[ridx[(size_t)n*PL_ + p]*8 + h];
      attn[((size_t)bh*N_ + n)*58 + 9 + p] = acc[nj][reg] + bias;
    }
  }
}

// ---------------- softmax over 58 ----------------
__global__ __launch_bounds__(256) void softmax_kernel(float* __restrict__ attn){
  int row  = blockIdx.x*4 + (threadIdx.x>>6);
  int lane = threadIdx.x & 63;
  float* p = attn + (size_t)row*58;
  float v = (lane<58) ? p[lane] : -1e30f;
  float mx = rmax64(v);
  float e = (lane<58) ? expf(v-mx) : 0.f;
  float s = rsum64(e);
  if (lane<58) p[lane] = e/s;
}

// ---------------- builders ----------------
__global__ __launch_bounds__(256) void build_w72(const float* __restrict__ lt, float* __restrict__ w72){
  int r = blockIdx.x, c = threadIdx.x;    // r in [0,72)
  int h = r/9, l = r - h*9;
  w72[(size_t)r*256 + c] = ((c>>5) == h) ? lt[((size_t)(h*32 + (c&31)))*9 + l] : 0.f;
}
__global__ __launch_bounds__(256) void build_dwwT(const float* __restrict__ dww, float* __restrict__ dwwT){
  int l = blockIdx.x;                     // [0,9)
  for (int f=threadIdx.x; f<684; f+=256)
    dwwT[(size_t)l*684 + f] = (f < HF_) ? dww[(size_t)f*9 + l] : 0.f;
}

// ---------------- x_local + x_pool -> out, no cross-lane ops ----------------
__global__ __launch_bounds__(256) void xout_v2(const float* __restrict__ qlt,
                                               const float* __restrict__ attn,
                                               const float* __restrict__ kv,
                                               const float* __restrict__ kvp2,
                                               float* __restrict__ out){
  __shared__ float coef[8][64];   // [0..8]=local(+qlt), [12..60]=pool
  int row = blockIdx.x; int b = row / N_; int n = row - b*N_;
  int y = n / WW, x = n - y*WW;
  int tid = threadIdx.x;
  for (int i=tid; i<8*58; i+=256){
    int h = i/58, j = i - h*58;
    float v = attn[((size_t)((b<<3)+h)*N_ + n)*58 + j];
    if (j < 9) coef[h][j] = v + qlt[(size_t)row*72 + h*9 + j];
    else       coef[h][j+3] = v;
  }
  __syncthreads();
  int h = tid>>5;
  float acc = 0.f;
  // local: 9 gathers, coefs via 2x float4 + 1 scalar
  float4 cA = *(float4*)&coef[h][0];
  float4 cB = *(float4*)&coef[h][4];
  float c8  = coef[h][8];
  float lc[9] = {cA.x,cA.y,cA.z,cA.w,cB.x,cB.y,cB.z,cB.w,c8};
  #pragma unroll
  for (int l=0;l<9;l++){
    int yy = y + l/3 - 1, xx = x + l%3 - 1;
    if (yy>=0 && yy<HH && xx>=0 && xx<WW)
      acc += lc[l] * kv[((size_t)(b*N_ + yy*WW + xx))*512 + 256 + tid];
  }
  // pool: 12 float4 coef reads + 1 scalar
  const float* pb = kvp2 + (size_t)b*PL_*512 + 256 + tid;
  #pragma unroll
  for (int pc=0;pc<12;pc++){
    float4 c4 = *(float4*)&coef[h][12 + pc*4];
    acc += c4.x*pb[(size_t)(pc*4+0)*512];
    acc += c4.y*pb[(size_t)(pc*4+1)*512];
    acc += c4.z*pb[(size_t)(pc*4+2)*512];
    acc += c4.w*pb[(size_t)(pc*4+3)*512];
  }
  acc += coef[h][60]*pb[(size_t)48*512];
  out[(size_t)row*C_ + tid] = acc;
}

// ---------------- depthwise 3x3 + gelu gate, float4 over channels ----------------
__global__ __launch_bounds__(256) void dwconv_v2(const float* __restrict__ hsrc,
                                                 const float* __restrict__ dwwT,
                                                 const float* __restrict__ dwb,
                                                 float* __restrict__ hg){
  int gidx = blockIdx.x*256 + threadIdx.x;
  if (gidx >= MROWS*171) return;
  int pix = gidx/171, g = gidx - pix*171;
  int b = pix / N_, n = pix - b*N_;
  int y = n / WW, x = n - y*WW;
  int f = g*4;
  const float* hb = hsrc + (size_t)b*N_*1364;
  if (g < 170){
    float4 s = *(const float4*)(dwb + f);
    #pragma unroll
    for (int l=0;l<9;l++){
      int yy = y + l/3 - 1, xx = x + l%3 - 1;
      if (yy>=0 && yy<HH && xx>=0 && xx<WW){
        float4 hv = *(const float4*)(hb + (size_t)(yy*WW+xx)*1364 + f);
        float4 wv = *(const float4*)(dwwT + (size_t)l*684 + f);
        s.x = fmaf(hv.x, wv.x, s.x);
        s.y = fmaf(hv.y, wv.y, s.y);
        s.z = fmaf(hv.z, wv.z, s.z);
        s.w = fmaf(hv.w, wv.w, s.w);
      }
    }
    const float* vp = hsrc + (size_t)pix*1364 + HF_ + f;
    float2 v0 = *(const float2*)vp, v1 = *(const float2*)(vp+2);
    float4 o;
    o.x = gelu_f(s.x)*v0.x; o.y = gelu_f(s.y)*v0.y;
    o.z = gelu_f(s.z)*v1.x; o.w = gelu_f(s.w)*v1.y;
    *(float4*)(hg + (size_t)pix*HGLD + f) = o;
  } else {
    #pragma unroll
    for (int c=0;c<2;c++){
      int ff = 680 + c;
      float s = dwb[ff];
      #pragma unroll
      for (int l=0;l<9;l++){
        int yy = y + l/3 - 1, xx = x + l%3 - 1;
        if (yy>=0 && yy<HH && xx>=0 && xx<WW)
          s += hb[(size_t)(yy*WW+xx)*1364 + ff] * dwwT[(size_t)l*684 + ff];
      }
      hg[(size_t)pix*HGLD + ff] = gelu_f(s) * hsrc[(size_t)pix*1364 + HF_ + ff];
    }
  }
}

extern "C" void kernel_launch(void* const* d_in, const int* in_sizes, int n_in,
                              void* d_out, int out_size, void* d_ws, size_t ws_size,
                              hipStream_t stream) {
  const float* x    = (const float*)d_in[0];
  const float* rct  = (const float*)d_in[1];
  const float* sls  = (const float*)d_in[2];
  const float* n1w  = (const float*)d_in[3];
  const float* n1b  = (const float*)d_in[4];
  const float* q_w  = (const float*)d_in[5];
  const float* q_b  = (const float*)d_in[6];
  const float* kv_w = (const float*)d_in[7];
  const float* kv_b = (const float*)d_in[8];
  const float* temp = (const float*)d_in[9];
  const float* qe   = (const float*)d_in[10];
  const float* rpb  = (const float*)d_in[11];
  const float* lt   = (const float*)d_in[12];
  const float* lb   = (const float*)d_in[13];
  const float* sr_w = (const float*)d_in[14];
  const float* sr_b = (const float*)d_in[15];
  const float* npw  = (const float*)d_in[16];
  const float* npb  = (const float*)d_in[17];
  const float* c1w  = (const float*)d_in[18];
  const float* c1b  = (const float*)d_in[19];
  const float* c2w  = (const float*)d_in[20];
  const float* c2b  = (const float*)d_in[21];
  const float* pw   = (const float*)d_in[22];
  const float* pb   = (const float*)d_in[23];
  const float* n2w  = (const float*)d_in[24];
  const float* n2b  = (const float*)d_in[25];
  const float* f1w  = (const float*)d_in[26];
  const float* f1b  = (const float*)d_in[27];
  const float* dww  = (const float*)d_in[28];
  const float* dwb  = (const float*)d_in[29];
  const float* f2w  = (const float*)d_in[30];
  const float* f2bb = (const float*)d_in[31];
  const int*  ridx  = (const int*)d_in[32];
  float* outp = (float*)d_out;

  char* ws = (char*)d_ws;
  constexpr size_t SZ_BNC  = (size_t)MROWS*C_*4;
  constexpr size_t SZ_KV   = (size_t)MROWS*512*4;
  constexpr size_t SZ_ATTN = (size_t)B_*NH_*N_*58*4;
  size_t o_xn   = 0;
  size_t o_qn   = o_xn   + SZ_BNC;
  size_t o_qs   = o_qn   + SZ_BNC;
  size_t o_kv   = o_qs   + SZ_BNC;
  size_t o_attn = o_kv   + SZ_KV;
  size_t o_xsr  = o_attn + SZ_ATTN;
  size_t o_xpln = o_xsr  + SZ_BNC;
  size_t o_kvp2 = o_xpln + (size_t)B_*PL_*C_*4;
  size_t o_cpb  = o_kvp2 + (size_t)B_*PL_*512*4;
  size_t o_out  = o_cpb  + (size_t)1024*8*4;
  size_t o_x2   = o_out  + SZ_BNC;
  size_t o_h    = o_kv;            // 136.9MB, spans kv..outb-start; dead regions at step>=17
  size_t o_hg   = 0;               // 69.0MB over xn+qn (dead after 17)
  size_t o_qlt  = o_xsr;           // qlt 7.23MB over xsr (dead after step 7; region free until 17)
  size_t o_w72  = o_xsr + (size_t)MROWS*72*4;       // 73728 B, same window
  size_t o_dwwT = (size_t)72*1024*1024;             // in qs-region tail (dead after 12), outside hg/hbuf

  float* xn   = (float*)(ws + o_xn);
  float* qbuf = (float*)(ws + o_qn);
  float* qsc  = (float*)(ws + o_qs);
  float* kv   = (float*)(ws + o_kv);
  float* attn = (float*)(ws + o_attn);
  float* xsr  = (float*)(ws + o_xsr);
  float* xpln = (float*)(ws + o_xpln);
  float* kvp2 = (float*)(ws + o_kvp2);
  float* cpb  = (float*)(ws + o_cpb);
  float* outb = (float*)(ws + o_out);
  float* x2   = (float*)(ws + o_x2);
  float* hbuf = (float*)(ws + o_h);
  float* hg   = (float*)(ws + o_hg);
  float* qlt  = (float*)(ws + o_qlt);
  float* w72  = (float*)(ws + o_w72);
  float* dwwT = (float*)(ws + o_dwwT);

  // 1. xn = LN(x)
  ln_kernel<<<MROWS, 256, 0, stream>>>(x, n1w, n1b, xn);
  // 2. q = xn @ q_w^T + q_b
  mfma_gemm<0,0><<<dim3(196,2), 256, 0, stream>>>(xn, C_, q_w, q_b, nullptr, qbuf, MROWS, 256, 256);
  // 3. kv = xn @ kv_w^T + kv_b
  mfma_gemm<0,0><<<dim3(196,4), 256, 0, stream>>>(xn, C_, kv_w, kv_b, nullptr, kv, MROWS, 512, 256);
  // 4. q_norm (in place) + q_scaled
  qpost_kernel<<<MROWS, 256, 0, stream>>>(qbuf, qe, temp, sls, qsc);
  // 5. k l2norm in place
  knorm_kernel<<<MROWS, 256, 0, stream>>>(kv);
  // 6. x_sr = gelu(xn @ sr_w^T + sr_b)
  mfma_gemm<1,0><<<dim3(196,2), 256, 0, stream>>>(xn, C_, sr_w, sr_b, nullptr, xsr, MROWS, 256, 256);
  // 7. 8x8 avg pool + LN(normp)
  pool_ln_kernel<<<B_*PL_, 256, 0, stream>>>(xsr, npw, npb, xpln);
  // 8. kvp2 = xpln @ kv_w^T + kv_b
  mfma_gemm<0,0><<<dim3(4,4), 256, 0, stream>>>(xpln, C_, kv_w, kv_b, nullptr, kvp2, B_*PL_, 512, 256);
  // 9. k_pool l2norm in place
  knorm_kernel<<<B_*PL_, 256, 0, stream>>>(kvp2);
  // 10. CPB MLP
  cpb_kernel<<<1024, 256, 0, stream>>>(rct, c1w, c1b, c2w, c2b, cpb);
  // 10b. block-diag learnable-token weight + qlt = qn @ w72^T + lb
  build_w72<<<72, 256, 0, stream>>>(lt, w72);
  mfma_gemm<0,0><<<dim3(196,1), 256, 0, stream>>>(qbuf, C_, w72, lb, nullptr, qlt, MROWS, 72, 256);
  // 11. local attention logits
  attn_local_kernel<<<MROWS, 256, 0, stream>>>(qsc, kv, rpb, attn);
  // 12. pooled attention logits (MFMA)
  attn_pool_mfma<<<dim3(49,64), 256, 0, stream>>>(qsc, kvp2, cpb, ridx, attn);
  // 13. softmax over 58
  softmax_kernel<<<(B_*NH_*N_)/4, 256, 0, stream>>>(attn);
  // 14. x_local + x_pool -> out
  xout_v2<<<MROWS, 256, 0, stream>>>(qlt, attn, kv, kvp2, outb);
  // 15. x2 = x + out @ proj_w^T + proj_b
  mfma_gemm<0,1><<<dim3(196,2), 256, 0, stream>>>(outb, C_, pw, pb, x, x2, MROWS, 256, 256);
  // 16. xn2 = LN(x2)
  ln_kernel<<<MROWS, 256, 0, stream>>>(x2, n2w, n2b, xn);
  // 17. h = xn2 @ fc1_w^T + fc1_b
  mfma_gemm<0,0><<<dim3(196,11), 256, 0, stream>>>(xn, C_, f1w, f1b, nullptr, hbuf, MROWS, 1364, 256);
  // 17b. transposed dw weights (region dead only after step 12, so build here)
  build_dwwT<<<9, 256, 0, stream>>>(dww, dwwT);
  // 18. hg = gelu(dwconv(h1)+dwb) * v
  dwconv_v2<<<(MROWS*171+255)/256, 256, 0, stream>>>(hbuf, dwwT, dwb, hg);
  // 19. out = x2 + hg @ fc2_w^T + fc2_b
  mfma_gemm<0,1><<<dim3(196,2), 256, 0, stream>>>(hg, HGLD, f2w, f2bb, x2, outp, MROWS, 256, 682);
}

// Round 5
// 952.036 us; speedup vs baseline: 2.5128x; 1.1932x over previous
//
#include <hip/hip_runtime.h>
#include <math.h>

#define B_   8
#define N_   3136
#define C_   256
#define NH_  8
#define HD_  32
#define LL_  9
#define PL_  49
#define HF_  682
#define HH   56
#define WW   56
#define MROWS (B_*N_)   // 25088
#define HGLD  688       // padded row stride for hg

typedef short bf16x8 __attribute__((ext_vector_type(8)));
typedef float f32x4  __attribute__((ext_vector_type(4)));

static __device__ __forceinline__ float gelu_f(float x){ return 0.5f*x*(1.0f+erff(x*0.70710678118654752f)); }
static __device__ __forceinline__ unsigned short f2bf(float f){
  union { float f; unsigned u; } x; x.f = f;
  unsigned r = (x.u + 0x7FFFu + ((x.u >> 16) & 1u)) >> 16;
  return (unsigned short)r;
}
static __device__ __forceinline__ float rsum32(float v){
  #pragma unroll
  for (int m=16;m>0;m>>=1) v += __shfl_xor(v,m,32);
  return v;
}
static __device__ __forceinline__ float rsum64(float v){
  #pragma unroll
  for (int m=32;m>0;m>>=1) v += __shfl_xor(v,m,64);
  return v;
}
static __device__ __forceinline__ float rmax64(float v){
  #pragma unroll
  for (int m=32;m>0;m>>=1) v = fmaxf(v,__shfl_xor(v,m,64));
  return v;
}

// ---------------- LayerNorm over C=256, one block per row ----------------
__global__ __launch_bounds__(256) void ln_kernel(const float* __restrict__ in,
                                                 const float* __restrict__ w,
                                                 const float* __restrict__ bsh,
                                                 float* __restrict__ out){
  int row = blockIdx.x, tid = threadIdx.x;
  float v = in[(size_t)row*C_+tid];
  float s = rsum64(v), q = rsum64(v*v);
  __shared__ float s1[4], s2[4];
  if ((tid&63)==0){ s1[tid>>6]=s; s2[tid>>6]=q; }
  __syncthreads();
  float ts=s1[0]+s1[1]+s1[2]+s1[3];
  float tq=s2[0]+s2[1]+s2[2]+s2[3];
  float m = ts*(1.0f/C_);
  float var = tq*(1.0f/C_)-m*m;
  float inv = rsqrtf(var+1e-5f);
  out[(size_t)row*C_+tid] = (v-m)*inv*w[tid]+bsh[tid];
}

// ---------------- bf16 MFMA GEMM (128x128 tile, BK=32) — for large Nt ----------------
template<int ACT, int RES>
__global__ __launch_bounds__(256) void mfma_gemm(const float* __restrict__ A, int lda,
                                                 const float* __restrict__ W,
                                                 const float* __restrict__ bias,
                                                 const float* __restrict__ res,
                                                 float* __restrict__ out,
                                                 int M, int Nt, int K){
  constexpr int LDT = 40;
  __shared__ unsigned short As[128*LDT];
  __shared__ unsigned short Bs[128*LDT];
  int tid = threadIdx.x, lane = tid & 63, wave = tid >> 6;
  int m0 = blockIdx.x*128, n0 = blockIdx.y*128;
  int wm = (wave>>1)*64, wn = (wave&1)*64;
  f32x4 acc[4][4];
  #pragma unroll
  for (int i=0;i<4;i++)
    #pragma unroll
    for (int j=0;j<4;j++) acc[i][j] = (f32x4){0.f,0.f,0.f,0.f};

  const bool w4 = ((K & 3) == 0);
  const int Kt = (K + 31) & ~31;
  const int l15 = lane & 15, quad = lane >> 4;

  for (int k0=0; k0<Kt; k0+=32){
    #pragma unroll
    for (int i=0;i<4;i++){
      int chunk = i*256 + tid;
      int r = chunk >> 3, c = (chunk & 7)*4;
      int gk = k0 + c, gr = m0 + r;
      float4 v = {0.f,0.f,0.f,0.f};
      if (gr < M){
        const float* ap = A + (size_t)gr*lda;
        if (gk + 4 <= K) v = *(const float4*)(ap + gk);
        else if (gk < K){
          v.x = ap[gk];
          if (gk+1 < K) v.y = ap[gk+1];
          if (gk+2 < K) v.z = ap[gk+2];
        }
      }
      ushort4 o; o.x=f2bf(v.x); o.y=f2bf(v.y); o.z=f2bf(v.z); o.w=f2bf(v.w);
      *(ushort4*)(&As[r*LDT + c]) = o;
    }
    if (w4){
      #pragma unroll
      for (int i=0;i<4;i++){
        int chunk = i*256 + tid;
        int r = chunk >> 3, c = (chunk & 7)*4;
        int gk = k0 + c, gn = n0 + r;
        float4 v = {0.f,0.f,0.f,0.f};
        if (gn < Nt){
          const float* wp = W + (size_t)gn*K;
          if (gk + 4 <= K) v = *(const float4*)(wp + gk);
          else if (gk < K){
            v.x = wp[gk];
            if (gk+1 < K) v.y = wp[gk+1];
            if (gk+2 < K) v.z = wp[gk+2];
          }
        }
        ushort4 o; o.x=f2bf(v.x); o.y=f2bf(v.y); o.z=f2bf(v.z); o.w=f2bf(v.w);
        *(ushort4*)(&Bs[r*LDT + c]) = o;
      }
    } else {
      #pragma unroll
      for (int i=0;i<8;i++){
        int chunk = i*256 + tid;
        int r = chunk >> 4, c = (chunk & 15)*2;
        int gk = k0 + c, gn = n0 + r;
        float2 v = {0.f,0.f};
        if (gn < Nt){
          const float* wp = W + (size_t)gn*K;
          if (gk + 2 <= K) v = *(const float2*)(wp + gk);
          else if (gk < K) v.x = wp[gk];
        }
        ushort2 o; o.x=f2bf(v.x); o.y=f2bf(v.y);
        *(ushort2*)(&Bs[r*LDT + c]) = o;
      }
    }
    __syncthreads();
    bf16x8 af[4], bfr[4];
    #pragma unroll
    for (int mi=0;mi<4;mi++)
      af[mi] = *(bf16x8*)(&As[(wm + mi*16 + l15)*LDT + quad*8]);
    #pragma unroll
    for (int nj=0;nj<4;nj++)
      bfr[nj] = *(bf16x8*)(&Bs[(wn + nj*16 + l15)*LDT + quad*8]);
    #pragma unroll
    for (int mi=0;mi<4;mi++)
      #pragma unroll
      for (int nj=0;nj<4;nj++)
        acc[mi][nj] = __builtin_amdgcn_mfma_f32_16x16x32_bf16(af[mi], bfr[nj], acc[mi][nj], 0,0,0);
    __syncthreads();
  }
  int rbase = quad*4;
  #pragma unroll
  for (int nj=0;nj<4;nj++){
    int gc = n0 + wn + nj*16 + l15;
    if (gc >= Nt) continue;
    float bv = bias[gc];
    #pragma unroll
    for (int mi=0;mi<4;mi++){
      #pragma unroll
      for (int reg=0;reg<4;reg++){
        int gr = m0 + wm + mi*16 + rbase + reg;
        if (gr >= M) continue;
        float v = acc[mi][nj][reg] + bv;
        if (ACT==1) v = gelu_f(v);
        if (RES)   v += res[(size_t)gr*Nt + gc];
        out[(size_t)gr*Nt + gc] = v;
      }
    }
  }
}

// ---------------- bf16 MFMA GEMM (64x64 tile, BK=32) — for small Nt / high block count ----
template<int ACT, int RES>
__global__ __launch_bounds__(256) void mfma_gemm64(const float* __restrict__ A, int lda,
                                                   const float* __restrict__ W,
                                                   const float* __restrict__ bias,
                                                   const float* __restrict__ res,
                                                   float* __restrict__ out,
                                                   int M, int Nt, int K){
  constexpr int LDT = 40;
  __shared__ unsigned short As[64*LDT];
  __shared__ unsigned short Bs[64*LDT];
  int tid = threadIdx.x, lane = tid & 63, wave = tid >> 6;
  int m0 = blockIdx.x*64, n0 = blockIdx.y*64;
  int wm = (wave>>1)*32, wn = (wave&1)*32;
  f32x4 acc[2][2];
  #pragma unroll
  for (int i=0;i<2;i++)
    #pragma unroll
    for (int j=0;j<2;j++) acc[i][j] = (f32x4){0.f,0.f,0.f,0.f};

  const bool w4 = ((K & 3) == 0);
  const int Kt = (K + 31) & ~31;
  const int l15 = lane & 15, quad = lane >> 4;

  for (int k0=0; k0<Kt; k0+=32){
    // stage A 64x32
    #pragma unroll
    for (int i=0;i<2;i++){
      int chunk = i*256 + tid;
      int r = chunk >> 3, c = (chunk & 7)*4;
      int gk = k0 + c, gr = m0 + r;
      float4 v = {0.f,0.f,0.f,0.f};
      if (gr < M){
        const float* ap = A + (size_t)gr*lda;
        if (gk + 4 <= K) v = *(const float4*)(ap + gk);
        else if (gk < K){
          v.x = ap[gk];
          if (gk+1 < K) v.y = ap[gk+1];
          if (gk+2 < K) v.z = ap[gk+2];
        }
      }
      ushort4 o; o.x=f2bf(v.x); o.y=f2bf(v.y); o.z=f2bf(v.z); o.w=f2bf(v.w);
      *(ushort4*)(&As[r*LDT + c]) = o;
    }
    // stage W 64x32
    if (w4){
      #pragma unroll
      for (int i=0;i<2;i++){
        int chunk = i*256 + tid;
        int r = chunk >> 3, c = (chunk & 7)*4;
        int gk = k0 + c, gn = n0 + r;
        float4 v = {0.f,0.f,0.f,0.f};
        if (gn < Nt){
          const float* wp = W + (size_t)gn*K;
          if (gk + 4 <= K) v = *(const float4*)(wp + gk);
          else if (gk < K){
            v.x = wp[gk];
            if (gk+1 < K) v.y = wp[gk+1];
            if (gk+2 < K) v.z = wp[gk+2];
          }
        }
        ushort4 o; o.x=f2bf(v.x); o.y=f2bf(v.y); o.z=f2bf(v.z); o.w=f2bf(v.w);
        *(ushort4*)(&Bs[r*LDT + c]) = o;
      }
    } else {
      #pragma unroll
      for (int i=0;i<4;i++){
        int chunk = i*256 + tid;
        int r = chunk >> 4, c = (chunk & 15)*2;
        int gk = k0 + c, gn = n0 + r;
        float2 v = {0.f,0.f};
        if (gn < Nt){
          const float* wp = W + (size_t)gn*K;
          if (gk + 2 <= K) v = *(const float2*)(wp + gk);
          else if (gk < K) v.x = wp[gk];
        }
        ushort2 o; o.x=f2bf(v.x); o.y=f2bf(v.y);
        *(ushort2*)(&Bs[r*LDT + c]) = o;
      }
    }
    __syncthreads();
    bf16x8 af[2], bfr[2];
    #pragma unroll
    for (int mi=0;mi<2;mi++)
      af[mi] = *(bf16x8*)(&As[(wm + mi*16 + l15)*LDT + quad*8]);
    #pragma unroll
    for (int nj=0;nj<2;nj++)
      bfr[nj] = *(bf16x8*)(&Bs[(wn + nj*16 + l15)*LDT + quad*8]);
    #pragma unroll
    for (int mi=0;mi<2;mi++)
      #pragma unroll
      for (int nj=0;nj<2;nj++)
        acc[mi][nj] = __builtin_amdgcn_mfma_f32_16x16x32_bf16(af[mi], bfr[nj], acc[mi][nj], 0,0,0);
    __syncthreads();
  }
  int rbase = quad*4;
  #pragma unroll
  for (int nj=0;nj<2;nj++){
    int gc = n0 + wn + nj*16 + l15;
    if (gc >= Nt) continue;
    float bv = bias[gc];
    #pragma unroll
    for (int mi=0;mi<2;mi++){
      #pragma unroll
      for (int reg=0;reg<4;reg++){
        int gr = m0 + wm + mi*16 + rbase + reg;
        if (gr >= M) continue;
        float v = acc[mi][nj][reg] + bv;
        if (ACT==1) v = gelu_f(v);
        if (RES)   v += res[(size_t)gr*Nt + gc];
        out[(size_t)gr*Nt + gc] = v;
      }
    }
  }
}

// ---------------- q post ----------------
__global__ __launch_bounds__(256) void qpost_kernel(float* __restrict__ q,
                                                    const float* __restrict__ qe,
                                                    const float* __restrict__ temp,
                                                    const float* __restrict__ sls,
                                                    float* __restrict__ qs_out){
  int row = blockIdx.x, tid = threadIdx.x, h = tid>>5;
  size_t idx = (size_t)row*C_ + tid;
  float v = q[idx];
  float ss = rsum32(v*v);
  float qn = v / fmaxf(sqrtf(ss), 1e-12f);
  q[idx] = qn;
  float t  = temp[h];
  float sp = log1pf(expf(t));
  float scale = sp * sls[0];
  qs_out[idx] = (qn + qe[tid])*scale;
}

// ---------------- k l2norm in place ----------------
__global__ __launch_bounds__(256) void knorm_kernel(float* __restrict__ kv){
  int row = blockIdx.x, tid = threadIdx.x;
  size_t idx = (size_t)row*512 + tid;
  float v = kv[idx];
  float ss = rsum32(v*v);
  kv[idx] = v / fmaxf(sqrtf(ss), 1e-12f);
}

// ---------------- 8x8 avg pool + LN ----------------
__global__ __launch_bounds__(256) void pool_ln_kernel(const float* __restrict__ xsr,
                                                      const float* __restrict__ w,
                                                      const float* __restrict__ bsh,
                                                      float* __restrict__ out){
  int blk = blockIdx.x; int b = blk/PL_; int p = blk%PL_;
  int py = p/7, px = p%7;
  int o = threadIdx.x;
  float s = 0.f;
  for (int iy=0;iy<8;iy++){
    const float* rowp = xsr + ((size_t)(b*N_ + (py*8+iy)*WW + px*8))*C_ + o;
    #pragma unroll
    for (int ix=0;ix<8;ix++) s += rowp[(size_t)ix*C_];
  }
  s *= (1.0f/64.0f);
  float su = rsum64(s), sq = rsum64(s*s);
  __shared__ float s1[4], s2[4];
  if ((o&63)==0){ s1[o>>6]=su; s2[o>>6]=sq; }
  __syncthreads();
  float ts=s1[0]+s1[1]+s1[2]+s1[3];
  float tq=s2[0]+s2[1]+s2[2]+s2[3];
  float m = ts*(1.0f/256.0f), var = tq*(1.0f/256.0f)-m*m;
  float inv = rsqrtf(var+1e-5f);
  out[(size_t)blk*C_+o] = (s-m)*inv*w[o]+bsh[o];
}

// ---------------- CPB MLP ----------------
__global__ __launch_bounds__(256) void cpb_kernel(const float* __restrict__ rct,
                                                  const float* __restrict__ w1,
                                                  const float* __restrict__ b1,
                                                  const float* __restrict__ w2,
                                                  const float* __restrict__ b2v,
                                                  float* __restrict__ cpb){
  __shared__ float r[512];
  int t = blockIdx.x, tid = threadIdx.x;
  float c0 = rct[t*2], c1 = rct[t*2+1];
  for (int j=tid;j<512;j+=256){
    float v = c0*w1[j*2] + c1*w1[j*2+1] + b1[j];
    r[j] = fmaxf(v, 0.f);
  }
  __syncthreads();
  int h = tid>>5, lane = tid&31;
  float s = 0.f;
  for (int j=lane;j<512;j+=32) s += r[j]*w2[h*512+j];
  s = rsum32(s);
  if (lane==0) cpb[t*8+h] = s + b2v[h];
}

// ---------------- local window attention logits ----------------
__global__ __launch_bounds__(256) void attn_local_kernel(const float* __restrict__ qs,
                                                         const float* __restrict__ kv,
                                                         const float* __restrict__ rpb,
                                                         float* __restrict__ attn){
  int blk = blockIdx.x; int b = blk / N_; int n = blk % N_;
  int y = n / WW, x = n % WW;
  int tid = threadIdx.x, h = tid>>5, d = tid&31;
  float q = qs[(size_t)blk*C_ + tid];
  float* arow = attn + ((size_t)(b*NH_+h)*N_ + n)*58;
  #pragma unroll
  for (int l=0;l<9;l++){
    int yy = y + l/3 - 1, xx = x + l%3 - 1;
    float kval = 0.f;
    if (yy>=0 && yy<HH && xx>=0 && xx<WW)
      kval = kv[((size_t)(b*N_ + yy*WW + xx))*512 + tid];
    float s = rsum32(q*kval);
    if (d==0) arow[l] = s + rpb[h*9+l];
  }
}

// ---------------- pooled attention logits via MFMA ----------------
__global__ __launch_bounds__(256) void attn_pool_mfma(const float* __restrict__ qs,
                                                      const float* __restrict__ kvp2,
                                                      const float* __restrict__ cpb,
                                                      const int* __restrict__ ridx,
                                                      float* __restrict__ attn){
  int tid = threadIdx.x, lane = tid & 63, wave = tid >> 6;
  int l15 = lane & 15, quad = lane >> 4;
  int bh = blockIdx.y, b = bh >> 3, h = bh & 7;
  int n0 = (blockIdx.x*4 + wave)*16;
  const float* qp = qs + ((size_t)(b*N_ + n0 + l15)*C_ + h*32 + quad*8);
  float4 a0 = *(const float4*)qp, a1 = *(const float4*)(qp+4);
  bf16x8 af;
  af[0]=(short)f2bf(a0.x); af[1]=(short)f2bf(a0.y); af[2]=(short)f2bf(a0.z); af[3]=(short)f2bf(a0.w);
  af[4]=(short)f2bf(a1.x); af[5]=(short)f2bf(a1.y); af[6]=(short)f2bf(a1.z); af[7]=(short)f2bf(a1.w);
  f32x4 acc[4];
  #pragma unroll
  for (int nj=0;nj<4;nj++){
    int p = nj*16 + l15;
    bf16x8 bfr = (bf16x8){0,0,0,0,0,0,0,0};
    if (p < PL_){
      const float* kp = kvp2 + ((size_t)(b*PL_ + p)*512 + h*32 + quad*8);
      float4 b0 = *(const float4*)kp, b1 = *(const float4*)(kp+4);
      bfr[0]=(short)f2bf(b0.x); bfr[1]=(short)f2bf(b0.y); bfr[2]=(short)f2bf(b0.z); bfr[3]=(short)f2bf(b0.w);
      bfr[4]=(short)f2bf(b1.x); bfr[5]=(short)f2bf(b1.y); bfr[6]=(short)f2bf(b1.z); bfr[7]=(short)f2bf(b1.w);
    }
    f32x4 z = (f32x4){0.f,0.f,0.f,0.f};
    acc[nj] = __builtin_amdgcn_mfma_f32_16x16x32_bf16(af, bfr, z, 0,0,0);
  }
  #pragma unroll
  for (int nj=0;nj<4;nj++){
    int p = nj*16 + l15;
    if (p >= PL_) continue;
    #pragma unroll
    for (int reg=0;reg<4;reg++){
      int n = n0 + quad*4 + reg;
      float bias = cpb[ridx[(size_t)n*PL_ + p]*8 + h];
      attn[((size_t)bh*N_ + n)*58 + 9 + p] = acc[nj][reg] + bias;
    }
  }
}

// ---------------- softmax over 58 ----------------
__global__ __launch_bounds__(256) void softmax_kernel(float* __restrict__ attn){
  int row  = blockIdx.x*4 + (threadIdx.x>>6);
  int lane = threadIdx.x & 63;
  float* p = attn + (size_t)row*58;
  float v = (lane<58) ? p[lane] : -1e30f;
  float mx = rmax64(v);
  float e = (lane<58) ? expf(v-mx) : 0.f;
  float s = rsum64(e);
  if (lane<58) p[lane] = e/s;
}

// ---------------- builders ----------------
__global__ __launch_bounds__(256) void build_w72(const float* __restrict__ lt, float* __restrict__ w72){
  int r = blockIdx.x, c = threadIdx.x;
  int h = r/9, l = r - h*9;
  w72[(size_t)r*256 + c] = ((c>>5) == h) ? lt[((size_t)(h*32 + (c&31)))*9 + l] : 0.f;
}
__global__ __launch_bounds__(256) void build_dwwT(const float* __restrict__ dww, float* __restrict__ dwwT){
  int l = blockIdx.x;
  for (int f=threadIdx.x; f<684; f+=256)
    dwwT[(size_t)l*684 + f] = (f < HF_) ? dww[(size_t)f*9 + l] : 0.f;
}

// ---------------- x_local + x_pool -> out ----------------
__global__ __launch_bounds__(256) void xout_v2(const float* __restrict__ qlt,
                                               const float* __restrict__ attn,
                                               const float* __restrict__ kv,
                                               const float* __restrict__ kvp2,
                                               float* __restrict__ out){
  __shared__ float coef[8][64];
  int row = blockIdx.x; int b = row / N_; int n = row - b*N_;
  int y = n / WW, x = n - y*WW;
  int tid = threadIdx.x;
  for (int i=tid; i<8*58; i+=256){
    int h = i/58, j = i - h*58;
    float v = attn[((size_t)((b<<3)+h)*N_ + n)*58 + j];
    if (j < 9) coef[h][j] = v + qlt[(size_t)row*72 + h*9 + j];
    else       coef[h][j+3] = v;
  }
  __syncthreads();
  int h = tid>>5;
  float acc = 0.f;
  float4 cA = *(float4*)&coef[h][0];
  float4 cB = *(float4*)&coef[h][4];
  float c8  = coef[h][8];
  float lc[9] = {cA.x,cA.y,cA.z,cA.w,cB.x,cB.y,cB.z,cB.w,c8};
  #pragma unroll
  for (int l=0;l<9;l++){
    int yy = y + l/3 - 1, xx = x + l%3 - 1;
    if (yy>=0 && yy<HH && xx>=0 && xx<WW)
      acc += lc[l] * kv[((size_t)(b*N_ + yy*WW + xx))*512 + 256 + tid];
  }
  const float* pb = kvp2 + (size_t)b*PL_*512 + 256 + tid;
  #pragma unroll
  for (int pc=0;pc<12;pc++){
    float4 c4 = *(float4*)&coef[h][12 + pc*4];
    acc += c4.x*pb[(size_t)(pc*4+0)*512];
    acc += c4.y*pb[(size_t)(pc*4+1)*512];
    acc += c4.z*pb[(size_t)(pc*4+2)*512];
    acc += c4.w*pb[(size_t)(pc*4+3)*512];
  }
  acc += coef[h][60]*pb[(size_t)48*512];
  out[(size_t)row*C_ + tid] = acc;
}

// ---------------- depthwise 3x3 + gelu gate ----------------
__global__ __launch_bounds__(256) void dwconv_v2(const float* __restrict__ hsrc,
                                                 const float* __restrict__ dwwT,
                                                 const float* __restrict__ dwb,
                                                 float* __restrict__ hg){
  int gidx = blockIdx.x*256 + threadIdx.x;
  if (gidx >= MROWS*171) return;
  int pix = gidx/171, g = gidx - pix*171;
  int b = pix / N_, n = pix - b*N_;
  int y = n / WW, x = n - y*WW;
  int f = g*4;
  const float* hb = hsrc + (size_t)b*N_*1364;
  if (g < 170){
    float4 s = *(const float4*)(dwb + f);
    #pragma unroll
    for (int l=0;l<9;l++){
      int yy = y + l/3 - 1, xx = x + l%3 - 1;
      if (yy>=0 && yy<HH && xx>=0 && xx<WW){
        float4 hv = *(const float4*)(hb + (size_t)(yy*WW+xx)*1364 + f);
        float4 wv = *(const float4*)(dwwT + (size_t)l*684 + f);
        s.x = fmaf(hv.x, wv.x, s.x);
        s.y = fmaf(hv.y, wv.y, s.y);
        s.z = fmaf(hv.z, wv.z, s.z);
        s.w = fmaf(hv.w, wv.w, s.w);
      }
    }
    const float* vp = hsrc + (size_t)pix*1364 + HF_ + f;
    float2 v0 = *(const float2*)vp, v1 = *(const float2*)(vp+2);
    float4 o;
    o.x = gelu_f(s.x)*v0.x; o.y = gelu_f(s.y)*v0.y;
    o.z = gelu_f(s.z)*v1.x; o.w = gelu_f(s.w)*v1.y;
    *(float4*)(hg + (size_t)pix*HGLD + f) = o;
  } else {
    #pragma unroll
    for (int c=0;c<2;c++){
      int ff = 680 + c;
      float s = dwb[ff];
      #pragma unroll
      for (int l=0;l<9;l++){
        int yy = y + l/3 - 1, xx = x + l%3 - 1;
        if (yy>=0 && yy<HH && xx>=0 && xx<WW)
          s += hb[(size_t)(yy*WW+xx)*1364 + ff] * dwwT[(size_t)l*684 + ff];
      }
      hg[(size_t)pix*HGLD + ff] = gelu_f(s) * hsrc[(size_t)pix*1364 + HF_ + ff];
    }
  }
}

extern "C" void kernel_launch(void* const* d_in, const int* in_sizes, int n_in,
                              void* d_out, int out_size, void* d_ws, size_t ws_size,
                              hipStream_t stream) {
  const float* x    = (const float*)d_in[0];
  const float* rct  = (const float*)d_in[1];
  const float* sls  = (const float*)d_in[2];
  const float* n1w  = (const float*)d_in[3];
  const float* n1b  = (const float*)d_in[4];
  const float* q_w  = (const float*)d_in[5];
  const float* q_b  = (const float*)d_in[6];
  const float* kv_w = (const float*)d_in[7];
  const float* kv_b = (const float*)d_in[8];
  const float* temp = (const float*)d_in[9];
  const float* qe   = (const float*)d_in[10];
  const float* rpb  = (const float*)d_in[11];
  const float* lt   = (const float*)d_in[12];
  const float* lb   = (const float*)d_in[13];
  const float* sr_w = (const float*)d_in[14];
  const float* sr_b = (const float*)d_in[15];
  const float* npw  = (const float*)d_in[16];
  const float* npb  = (const float*)d_in[17];
  const float* c1w  = (const float*)d_in[18];
  const float* c1b  = (const float*)d_in[19];
  const float* c2w  = (const float*)d_in[20];
  const float* c2b  = (const float*)d_in[21];
  const float* pw   = (const float*)d_in[22];
  const float* pb   = (const float*)d_in[23];
  const float* n2w  = (const float*)d_in[24];
  const float* n2b  = (const float*)d_in[25];
  const float* f1w  = (const float*)d_in[26];
  const float* f1b  = (const float*)d_in[27];
  const float* dww  = (const float*)d_in[28];
  const float* dwb  = (const float*)d_in[29];
  const float* f2w  = (const float*)d_in[30];
  const float* f2bb = (const float*)d_in[31];
  const int*  ridx  = (const int*)d_in[32];
  float* outp = (float*)d_out;

  char* ws = (char*)d_ws;
  constexpr size_t SZ_BNC  = (size_t)MROWS*C_*4;
  constexpr size_t SZ_KV   = (size_t)MROWS*512*4;
  constexpr size_t SZ_ATTN = (size_t)B_*NH_*N_*58*4;
  size_t o_xn   = 0;
  size_t o_qn   = o_xn   + SZ_BNC;
  size_t o_qs   = o_qn   + SZ_BNC;
  size_t o_kv   = o_qs   + SZ_BNC;
  size_t o_attn = o_kv   + SZ_KV;
  size_t o_xsr  = o_attn + SZ_ATTN;
  size_t o_xpln = o_xsr  + SZ_BNC;
  size_t o_kvp2 = o_xpln + (size_t)B_*PL_*C_*4;
  size_t o_cpb  = o_kvp2 + (size_t)B_*PL_*512*4;
  size_t o_out  = o_cpb  + (size_t)1024*8*4;
  size_t o_x2   = o_out  + SZ_BNC;
  size_t o_h    = o_kv;
  size_t o_hg   = 0;
  size_t o_qlt  = o_xsr;
  size_t o_w72  = o_xsr + (size_t)MROWS*72*4;
  size_t o_dwwT = (size_t)72*1024*1024;

  float* xn   = (float*)(ws + o_xn);
  float* qbuf = (float*)(ws + o_qn);
  float* qsc  = (float*)(ws + o_qs);
  float* kv   = (float*)(ws + o_kv);
  float* attn = (float*)(ws + o_attn);
  float* xsr  = (float*)(ws + o_xsr);
  float* xpln = (float*)(ws + o_xpln);
  float* kvp2 = (float*)(ws + o_kvp2);
  float* cpb  = (float*)(ws + o_cpb);
  float* outb = (float*)(ws + o_out);
  float* x2   = (float*)(ws + o_x2);
  float* hbuf = (float*)(ws + o_h);
  float* hg   = (float*)(ws + o_hg);
  float* qlt  = (float*)(ws + o_qlt);
  float* w72  = (float*)(ws + o_w72);
  float* dwwT = (float*)(ws + o_dwwT);

  // 1. xn = LN(x)
  ln_kernel<<<MROWS, 256, 0, stream>>>(x, n1w, n1b, xn);
  // 2. q = xn @ q_w^T + q_b
  mfma_gemm64<0,0><<<dim3(392,4), 256, 0, stream>>>(xn, C_, q_w, q_b, nullptr, qbuf, MROWS, 256, 256);
  // 3. kv = xn @ kv_w^T + kv_b
  mfma_gemm64<0,0><<<dim3(392,8), 256, 0, stream>>>(xn, C_, kv_w, kv_b, nullptr, kv, MROWS, 512, 256);
  // 4. q_norm (in place) + q_scaled
  qpost_kernel<<<MROWS, 256, 0, stream>>>(qbuf, qe, temp, sls, qsc);
  // 5. k l2norm in place
  knorm_kernel<<<MROWS, 256, 0, stream>>>(kv);
  // 6. x_sr = gelu(xn @ sr_w^T + sr_b)
  mfma_gemm64<1,0><<<dim3(392,4), 256, 0, stream>>>(xn, C_, sr_w, sr_b, nullptr, xsr, MROWS, 256, 256);
  // 7. 8x8 avg pool + LN(normp)
  pool_ln_kernel<<<B_*PL_, 256, 0, stream>>>(xsr, npw, npb, xpln);
  // 8. kvp2 = xpln @ kv_w^T + kv_b
  mfma_gemm64<0,0><<<dim3(7,8), 256, 0, stream>>>(xpln, C_, kv_w, kv_b, nullptr, kvp2, B_*PL_, 512, 256);
  // 9. k_pool l2norm in place
  knorm_kernel<<<B_*PL_, 256, 0, stream>>>(kvp2);
  // 10. CPB MLP
  cpb_kernel<<<1024, 256, 0, stream>>>(rct, c1w, c1b, c2w, c2b, cpb);
  // 10b. block-diag learnable-token weight + qlt
  build_w72<<<72, 256, 0, stream>>>(lt, w72);
  mfma_gemm64<0,0><<<dim3(392,2), 256, 0, stream>>>(qbuf, C_, w72, lb, nullptr, qlt, MROWS, 72, 256);
  // 11. local attention logits
  attn_local_kernel<<<MROWS, 256, 0, stream>>>(qsc, kv, rpb, attn);
  // 12. pooled attention logits (MFMA)
  attn_pool_mfma<<<dim3(49,64), 256, 0, stream>>>(qsc, kvp2, cpb, ridx, attn);
  // 13. softmax over 58
  softmax_kernel<<<(B_*NH_*N_)/4, 256, 0, stream>>>(attn);
  // 14. x_local + x_pool -> out
  xout_v2<<<MROWS, 256, 0, stream>>>(qlt, attn, kv, kvp2, outb);
  // 15. x2 = x + out @ proj_w^T + proj_b
  mfma_gemm64<0,1><<<dim3(392,4), 256, 0, stream>>>(outb, C_, pw, pb, x, x2, MROWS, 256, 256);
  // 16. xn2 = LN(x2)
  ln_kernel<<<MROWS, 256, 0, stream>>>(x2, n2w, n2b, xn);
  // 17. h = xn2 @ fc1_w^T + fc1_b
  mfma_gemm<0,0><<<dim3(196,11), 256, 0, stream>>>(xn, C_, f1w, f1b, nullptr, hbuf, MROWS, 1364, 256);
  // 17b. transposed dw weights
  build_dwwT<<<9, 256, 0, stream>>>(dww, dwwT);
  // 18. hg = gelu(dwconv(h1)+dwb) * v
  dwconv_v2<<<(MROWS*171+255)/256, 256, 0, stream>>>(hbuf, dwwT, dwb, hg);
  // 19. out = x2 + hg @ fc2_w^T + fc2_b
  mfma_gemm64<0,1><<<dim3(392,4), 256, 0, stream>>>(hg, HGLD, f2w, f2bb, x2, outp, MROWS, 256, 682);
}

// Round 6
// 730.670 us; speedup vs baseline: 3.2741x; 1.3030x over previous
//
#include <hip/hip_runtime.h>
#include <math.h>

#define B_   8
#define N_   3136
#define C_   256
#define NH_  8
#define HD_  32
#define LL_  9
#define PL_  49
#define HF_  682
#define HH   56
#define WW   56
#define MROWS (B_*N_)   // 25088
#define HGLD  688       // padded row stride for hg (bf16), cols 682..687 zeroed
#define F2LD  688       // padded ldw for fc2 weight (bf16)

typedef short          bf16x8 __attribute__((ext_vector_type(8)));
typedef unsigned short u16x8  __attribute__((ext_vector_type(8)));
typedef float          f32x4  __attribute__((ext_vector_type(4)));
typedef unsigned short u16;

static __device__ __forceinline__ float gelu_f(float x){ return 0.5f*x*(1.0f+erff(x*0.70710678118654752f)); }
static __device__ __forceinline__ u16 f2bf(float f){
  union { float f; unsigned u; } x; x.f = f;
  unsigned r = (x.u + 0x7FFFu + ((x.u >> 16) & 1u)) >> 16;
  return (u16)r;
}
static __device__ __forceinline__ float b2f(u16 u){
  union { unsigned u; float f; } x; x.u = ((unsigned)u) << 16;
  return x.f;
}
static __device__ __forceinline__ float rsum32(float v){
  #pragma unroll
  for (int m=16;m>0;m>>=1) v += __shfl_xor(v,m,32);
  return v;
}
static __device__ __forceinline__ float rsum64(float v){
  #pragma unroll
  for (int m=32;m>0;m>>=1) v += __shfl_xor(v,m,64);
  return v;
}
static __device__ __forceinline__ float rmax64(float v){
  #pragma unroll
  for (int m=32;m>0;m>>=1) v = fmaxf(v,__shfl_xor(v,m,64));
  return v;
}

// ---------------- weight conversion ----------------
__global__ __launch_bounds__(256) void cvt4_kernel(const float* __restrict__ src,
                                                   u16* __restrict__ dst, int n4){
  int i = blockIdx.x*256 + threadIdx.x;
  if (i >= n4) return;
  float4 v = *(const float4*)(src + (size_t)i*4);
  ushort4 o; o.x=f2bf(v.x); o.y=f2bf(v.y); o.z=f2bf(v.z); o.w=f2bf(v.w);
  *(ushort4*)(dst + (size_t)i*4) = o;
}
// pad K -> ldw with zeros
__global__ __launch_bounds__(256) void cvt_pad_kernel(const float* __restrict__ src,
                                                      u16* __restrict__ dst,
                                                      int rows, int K, int ldw){
  int i = blockIdx.x*256 + threadIdx.x;
  if (i >= rows*ldw) return;
  int r = i/ldw, k = i - r*ldw;
  dst[i] = (k < K) ? f2bf(src[(size_t)r*K + k]) : (u16)0;
}

// ---------------- LayerNorm over C=256 -> bf16 ----------------
__global__ __launch_bounds__(256) void ln_kernel(const float* __restrict__ in,
                                                 const float* __restrict__ w,
                                                 const float* __restrict__ bsh,
                                                 u16* __restrict__ out){
  int row = blockIdx.x, tid = threadIdx.x;
  float v = in[(size_t)row*C_+tid];
  float s = rsum64(v), q = rsum64(v*v);
  __shared__ float s1[4], s2[4];
  if ((tid&63)==0){ s1[tid>>6]=s; s2[tid>>6]=q; }
  __syncthreads();
  float ts=s1[0]+s1[1]+s1[2]+s1[3];
  float tq=s2[0]+s2[1]+s2[2]+s2[3];
  float m = ts*(1.0f/C_);
  float var = tq*(1.0f/C_)-m*m;
  float inv = rsqrtf(var+1e-5f);
  out[(size_t)row*C_+tid] = f2bf((v-m)*inv*w[tid]+bsh[tid]);
}

// ---------------- bf16-in GEMM, 64x64 tile, BK=32 ----------------
// A[M][lda] bf16 (cols K..lda-1 zeroed), W[Nt][ldw] bf16 (cols K..ldw-1 zeroed).
// OUTBF: 1 -> bf16 out, 0 -> f32 out. out ld = Nt.
template<int ACT, int RES, int OUTBF>
__global__ __launch_bounds__(256) void gemm64b(const u16* __restrict__ A, int lda,
                                               const u16* __restrict__ W, int ldw,
                                               const float* __restrict__ bias,
                                               const float* __restrict__ res,
                                               void* __restrict__ outv,
                                               int M, int Nt, int K){
  constexpr int LDT = 40;
  __shared__ u16 As[64*LDT];
  __shared__ u16 Bs[64*LDT];
  int tid = threadIdx.x, lane = tid & 63;
  int wave = tid >> 6;
  int m0 = blockIdx.x*64, n0 = blockIdx.y*64;
  int wm = (wave>>1)*32, wn = (wave&1)*32;
  f32x4 acc[2][2];
  #pragma unroll
  for (int i=0;i<2;i++)
    #pragma unroll
    for (int j=0;j<2;j++) acc[i][j] = (f32x4){0.f,0.f,0.f,0.f};

  const int Kt = (K + 31) & ~31;
  const int l15 = lane & 15, quad = lane >> 4;
  int r  = tid >> 2;             // 0..63
  int c8 = (tid & 3) * 8;        // 0,8,16,24

  for (int k0=0; k0<Kt; k0+=32){
    int gk = k0 + c8;
    u16x8 av = (u16x8){0,0,0,0,0,0,0,0};
    if (m0 + r < M && gk + 8 <= lda)
      av = *(const u16x8*)(A + (size_t)(m0+r)*lda + gk);
    *(u16x8*)(&As[r*LDT + c8]) = av;
    u16x8 bv = (u16x8){0,0,0,0,0,0,0,0};
    if (n0 + r < Nt && gk + 8 <= ldw)
      bv = *(const u16x8*)(W + (size_t)(n0+r)*ldw + gk);
    *(u16x8*)(&Bs[r*LDT + c8]) = bv;
    __syncthreads();
    bf16x8 af[2], bfr[2];
    #pragma unroll
    for (int mi=0;mi<2;mi++)
      af[mi] = *(bf16x8*)(&As[(wm + mi*16 + l15)*LDT + quad*8]);
    #pragma unroll
    for (int nj=0;nj<2;nj++)
      bfr[nj] = *(bf16x8*)(&Bs[(wn + nj*16 + l15)*LDT + quad*8]);
    #pragma unroll
    for (int mi=0;mi<2;mi++)
      #pragma unroll
      for (int nj=0;nj<2;nj++)
        acc[mi][nj] = __builtin_amdgcn_mfma_f32_16x16x32_bf16(af[mi], bfr[nj], acc[mi][nj], 0,0,0);
    __syncthreads();
  }
  int rbase = quad*4;
  #pragma unroll
  for (int nj=0;nj<2;nj++){
    int gc = n0 + wn + nj*16 + l15;
    if (gc >= Nt) continue;
    float bv = bias[gc];
    #pragma unroll
    for (int mi=0;mi<2;mi++){
      #pragma unroll
      for (int reg=0;reg<4;reg++){
        int gr = m0 + wm + mi*16 + rbase + reg;
        if (gr >= M) continue;
        float v = acc[mi][nj][reg] + bv;
        if (ACT==1) v = gelu_f(v);
        if (RES)   v += res[(size_t)gr*Nt + gc];
        if (OUTBF) ((u16*)outv)[(size_t)gr*Nt + gc] = f2bf(v);
        else       ((float*)outv)[(size_t)gr*Nt + gc] = v;
      }
    }
  }
}

// ---------------- bf16-in GEMM, 128x128 tile, BK=32 (fc1) ----------------
template<int ACT, int RES, int OUTBF>
__global__ __launch_bounds__(256) void gemm128b(const u16* __restrict__ A, int lda,
                                                const u16* __restrict__ W, int ldw,
                                                const float* __restrict__ bias,
                                                const float* __restrict__ res,
                                                void* __restrict__ outv,
                                                int M, int Nt, int K){
  constexpr int LDT = 40;
  __shared__ u16 As[128*LDT];
  __shared__ u16 Bs[128*LDT];
  int tid = threadIdx.x, lane = tid & 63, wave = tid >> 6;
  int m0 = blockIdx.x*128, n0 = blockIdx.y*128;
  int wm = (wave>>1)*64, wn = (wave&1)*64;
  f32x4 acc[4][4];
  #pragma unroll
  for (int i=0;i<4;i++)
    #pragma unroll
    for (int j=0;j<4;j++) acc[i][j] = (f32x4){0.f,0.f,0.f,0.f};

  const int Kt = (K + 31) & ~31;
  const int l15 = lane & 15, quad = lane >> 4;

  for (int k0=0; k0<Kt; k0+=32){
    #pragma unroll
    for (int i=0;i<2;i++){
      int chunk = i*256 + tid;
      int r = chunk >> 2, c8 = (chunk & 3)*8;
      int gk = k0 + c8;
      u16x8 av = (u16x8){0,0,0,0,0,0,0,0};
      if (m0 + r < M && gk + 8 <= lda)
        av = *(const u16x8*)(A + (size_t)(m0+r)*lda + gk);
      *(u16x8*)(&As[r*LDT + c8]) = av;
      u16x8 bv = (u16x8){0,0,0,0,0,0,0,0};
      if (n0 + r < Nt && gk + 8 <= ldw)
        bv = *(const u16x8*)(W + (size_t)(n0+r)*ldw + gk);
      *(u16x8*)(&Bs[r*LDT + c8]) = bv;
    }
    __syncthreads();
    bf16x8 af[4], bfr[4];
    #pragma unroll
    for (int mi=0;mi<4;mi++)
      af[mi] = *(bf16x8*)(&As[(wm + mi*16 + l15)*LDT + quad*8]);
    #pragma unroll
    for (int nj=0;nj<4;nj++)
      bfr[nj] = *(bf16x8*)(&Bs[(wn + nj*16 + l15)*LDT + quad*8]);
    #pragma unroll
    for (int mi=0;mi<4;mi++)
      #pragma unroll
      for (int nj=0;nj<4;nj++)
        acc[mi][nj] = __builtin_amdgcn_mfma_f32_16x16x32_bf16(af[mi], bfr[nj], acc[mi][nj], 0,0,0);
    __syncthreads();
  }
  int rbase = quad*4;
  #pragma unroll
  for (int nj=0;nj<4;nj++){
    int gc = n0 + wn + nj*16 + l15;
    if (gc >= Nt) continue;
    float bv = bias[gc];
    #pragma unroll
    for (int mi=0;mi<4;mi++){
      #pragma unroll
      for (int reg=0;reg<4;reg++){
        int gr = m0 + wm + mi*16 + rbase + reg;
        if (gr >= M) continue;
        float v = acc[mi][nj][reg] + bv;
        if (ACT==1) v = gelu_f(v);
        if (RES)   v += res[(size_t)gr*Nt + gc];
        if (OUTBF) ((u16*)outv)[(size_t)gr*Nt + gc] = f2bf(v);
        else       ((float*)outv)[(size_t)gr*Nt + gc] = v;
      }
    }
  }
}

// ---------------- q post (bf16 in place) ----------------
__global__ __launch_bounds__(256) void qpost_kernel(u16* __restrict__ q,
                                                    const float* __restrict__ qe,
                                                    const float* __restrict__ temp,
                                                    const float* __restrict__ sls,
                                                    u16* __restrict__ qs_out){
  int row = blockIdx.x, tid = threadIdx.x, h = tid>>5;
  size_t idx = (size_t)row*C_ + tid;
  float v = b2f(q[idx]);
  float ss = rsum32(v*v);
  float qn = v / fmaxf(sqrtf(ss), 1e-12f);
  q[idx] = f2bf(qn);
  float t  = temp[h];
  float sp = log1pf(expf(t));
  float scale = sp * sls[0];
  qs_out[idx] = f2bf((qn + qe[tid])*scale);
}

// ---------------- k l2norm in place (bf16, stride 512) ----------------
__global__ __launch_bounds__(256) void knorm_kernel(u16* __restrict__ kv){
  int row = blockIdx.x, tid = threadIdx.x;
  size_t idx = (size_t)row*512 + tid;
  float v = b2f(kv[idx]);
  float ss = rsum32(v*v);
  kv[idx] = f2bf(v / fmaxf(sqrtf(ss), 1e-12f));
}

// ---------------- 8x8 avg pool + LN (bf16 -> bf16) ----------------
__global__ __launch_bounds__(256) void pool_ln_kernel(const u16* __restrict__ xsr,
                                                      const float* __restrict__ w,
                                                      const float* __restrict__ bsh,
                                                      u16* __restrict__ out){
  int blk = blockIdx.x; int b = blk/PL_; int p = blk%PL_;
  int py = p/7, px = p%7;
  int o = threadIdx.x;
  float s = 0.f;
  for (int iy=0;iy<8;iy++){
    const u16* rowp = xsr + ((size_t)(b*N_ + (py*8+iy)*WW + px*8))*C_ + o;
    #pragma unroll
    for (int ix=0;ix<8;ix++) s += b2f(rowp[(size_t)ix*C_]);
  }
  s *= (1.0f/64.0f);
  float su = rsum64(s), sq = rsum64(s*s);
  __shared__ float s1[4], s2[4];
  if ((o&63)==0){ s1[o>>6]=su; s2[o>>6]=sq; }
  __syncthreads();
  float ts=s1[0]+s1[1]+s1[2]+s1[3];
  float tq=s2[0]+s2[1]+s2[2]+s2[3];
  float m = ts*(1.0f/256.0f), var = tq*(1.0f/256.0f)-m*m;
  float inv = rsqrtf(var+1e-5f);
  out[(size_t)blk*C_+o] = f2bf((s-m)*inv*w[o]+bsh[o]);
}

// ---------------- CPB MLP (f32) ----------------
__global__ __launch_bounds__(256) void cpb_kernel(const float* __restrict__ rct,
                                                  const float* __restrict__ w1,
                                                  const float* __restrict__ b1,
                                                  const float* __restrict__ w2,
                                                  const float* __restrict__ b2v,
                                                  float* __restrict__ cpb){
  __shared__ float r[512];
  int t = blockIdx.x, tid = threadIdx.x;
  float c0 = rct[t*2], c1 = rct[t*2+1];
  for (int j=tid;j<512;j+=256){
    float v = c0*w1[j*2] + c1*w1[j*2+1] + b1[j];
    r[j] = fmaxf(v, 0.f);
  }
  __syncthreads();
  int h = tid>>5, lane = tid&31;
  float s = 0.f;
  for (int j=lane;j<512;j+=32) s += r[j]*w2[h*512+j];
  s = rsum32(s);
  if (lane==0) cpb[t*8+h] = s + b2v[h];
}

// ---------------- local window attention logits (bf16 in) ----------------
__global__ __launch_bounds__(256) void attn_local_kernel(const u16* __restrict__ qs,
                                                         const u16* __restrict__ kv,
                                                         const float* __restrict__ rpb,
                                                         float* __restrict__ attn){
  int blk = blockIdx.x; int b = blk / N_; int n = blk % N_;
  int y = n / WW, x = n % WW;
  int tid = threadIdx.x, h = tid>>5, d = tid&31;
  float q = b2f(qs[(size_t)blk*C_ + tid]);
  float* arow = attn + ((size_t)(b*NH_+h)*N_ + n)*58;
  #pragma unroll
  for (int l=0;l<9;l++){
    int yy = y + l/3 - 1, xx = x + l%3 - 1;
    float kval = 0.f;
    if (yy>=0 && yy<HH && xx>=0 && xx<WW)
      kval = b2f(kv[((size_t)(b*N_ + yy*WW + xx))*512 + tid]);
    float s = rsum32(q*kval);
    if (d==0) arow[l] = s + rpb[h*9+l];
  }
}

// ---------------- pooled attention logits via MFMA (bf16 direct fragments) ----------------
__global__ __launch_bounds__(256) void attn_pool_mfma(const u16* __restrict__ qs,
                                                      const u16* __restrict__ kvp2,
                                                      const float* __restrict__ cpb,
                                                      const int* __restrict__ ridx,
                                                      float* __restrict__ attn){
  int tid = threadIdx.x, lane = tid & 63, wave = tid >> 6;
  int l15 = lane & 15, quad = lane >> 4;
  int bh = blockIdx.y, b = bh >> 3, h = bh & 7;
  int n0 = (blockIdx.x*4 + wave)*16;
  bf16x8 af = *(const bf16x8*)(qs + ((size_t)(b*N_ + n0 + l15)*C_ + h*32 + quad*8));
  f32x4 acc[4];
  #pragma unroll
  for (int nj=0;nj<4;nj++){
    int p = nj*16 + l15;
    bf16x8 bfr = (bf16x8){0,0,0,0,0,0,0,0};
    if (p < PL_)
      bfr = *(const bf16x8*)(kvp2 + ((size_t)(b*PL_ + p)*512 + h*32 + quad*8));
    f32x4 z = (f32x4){0.f,0.f,0.f,0.f};
    acc[nj] = __builtin_amdgcn_mfma_f32_16x16x32_bf16(af, bfr, z, 0,0,0);
  }
  #pragma unroll
  for (int nj=0;nj<4;nj++){
    int p = nj*16 + l15;
    if (p >= PL_) continue;
    #pragma unroll
    for (int reg=0;reg<4;reg++){
      int n = n0 + quad*4 + reg;
      float bias = cpb[ridx[(size_t)n*PL_ + p]*8 + h];
      attn[((size_t)bh*N_ + n)*58 + 9 + p] = acc[nj][reg] + bias;
    }
  }
}

// ---------------- softmax over 58 ----------------
__global__ __launch_bounds__(256) void softmax_kernel(float* __restrict__ attn){
  int row  = blockIdx.x*4 + (threadIdx.x>>6);
  int lane = threadIdx.x & 63;
  float* p = attn + (size_t)row*58;
  float v = (lane<58) ? p[lane] : -1e30f;
  float mx = rmax64(v);
  float e = (lane<58) ? expf(v-mx) : 0.f;
  float s = rsum64(e);
  if (lane<58) p[lane] = e/s;
}

// ---------------- builders ----------------
__global__ __launch_bounds__(256) void build_w72(const float* __restrict__ lt, u16* __restrict__ w72){
  int r = blockIdx.x, c = threadIdx.x;
  int h = r/9, l = r - h*9;
  w72[(size_t)r*256 + c] = ((c>>5) == h) ? f2bf(lt[((size_t)(h*32 + (c&31)))*9 + l]) : (u16)0;
}
__global__ __launch_bounds__(256) void build_dwwT(const float* __restrict__ dww, float* __restrict__ dwwT){
  int l = blockIdx.x;
  for (int f=threadIdx.x; f<684; f+=256)
    dwwT[(size_t)l*684 + f] = (f < HF_) ? dww[(size_t)f*9 + l] : 0.f;
}

// ---------------- x_local + x_pool -> out (bf16 out) ----------------
__global__ __launch_bounds__(256) void xout_v2(const float* __restrict__ qlt,
                                               const float* __restrict__ attn,
                                               const u16* __restrict__ kv,
                                               const u16* __restrict__ kvp2,
                                               u16* __restrict__ out){
  __shared__ float coef[8][64];
  int row = blockIdx.x; int b = row / N_; int n = row - b*N_;
  int y = n / WW, x = n - y*WW;
  int tid = threadIdx.x;
  for (int i=tid; i<8*58; i+=256){
    int h = i/58, j = i - h*58;
    float v = attn[((size_t)((b<<3)+h)*N_ + n)*58 + j];
    if (j < 9) coef[h][j] = v + qlt[(size_t)row*72 + h*9 + j];
    else       coef[h][j+3] = v;
  }
  __syncthreads();
  int h = tid>>5;
  float acc = 0.f;
  float4 cA = *(float4*)&coef[h][0];
  float4 cB = *(float4*)&coef[h][4];
  float c8  = coef[h][8];
  float lc[9] = {cA.x,cA.y,cA.z,cA.w,cB.x,cB.y,cB.z,cB.w,c8};
  #pragma unroll
  for (int l=0;l<9;l++){
    int yy = y + l/3 - 1, xx = x + l%3 - 1;
    if (yy>=0 && yy<HH && xx>=0 && xx<WW)
      acc += lc[l] * b2f(kv[((size_t)(b*N_ + yy*WW + xx))*512 + 256 + tid]);
  }
  const u16* pb = kvp2 + (size_t)b*PL_*512 + 256 + tid;
  #pragma unroll
  for (int pc=0;pc<12;pc++){
    float4 c4 = *(float4*)&coef[h][12 + pc*4];
    acc += c4.x*b2f(pb[(size_t)(pc*4+0)*512]);
    acc += c4.y*b2f(pb[(size_t)(pc*4+1)*512]);
    acc += c4.z*b2f(pb[(size_t)(pc*4+2)*512]);
    acc += c4.w*b2f(pb[(size_t)(pc*4+3)*512]);
  }
  acc += coef[h][60]*b2f(pb[(size_t)48*512]);
  out[(size_t)row*C_ + tid] = f2bf(acc);
}

// ---------------- depthwise 3x3 + gelu gate (bf16 in/out) ----------------
__global__ __launch_bounds__(256) void dwconv_v2(const u16* __restrict__ hsrc,
                                                 const float* __restrict__ dwwT,
                                                 const float* __restrict__ dwb,
                                                 u16* __restrict__ hg){
  int gidx = blockIdx.x*256 + threadIdx.x;
  if (gidx >= MROWS*171) return;
  int pix = gidx/171, g = gidx - pix*171;
  int b = pix / N_, n = pix - b*N_;
  int y = n / WW, x = n - y*WW;
  int f = g*4;
  const u16* hb = hsrc + (size_t)b*N_*1364;
  if (g < 170){
    float4 s = *(const float4*)(dwb + f);
    #pragma unroll
    for (int l=0;l<9;l++){
      int yy = y + l/3 - 1, xx = x + l%3 - 1;
      if (yy>=0 && yy<HH && xx>=0 && xx<WW){
        ushort4 hv = *(const ushort4*)(hb + (size_t)(yy*WW+xx)*1364 + f);
        float4 wv = *(const float4*)(dwwT + (size_t)l*684 + f);
        s.x = fmaf(b2f(hv.x), wv.x, s.x);
        s.y = fmaf(b2f(hv.y), wv.y, s.y);
        s.z = fmaf(b2f(hv.z), wv.z, s.z);
        s.w = fmaf(b2f(hv.w), wv.w, s.w);
      }
    }
    const u16* vp = hsrc + (size_t)pix*1364 + HF_ + f;
    ushort2 v0 = *(const ushort2*)vp, v1 = *(const ushort2*)(vp+2);
    ushort4 o;
    o.x = f2bf(gelu_f(s.x)*b2f(v0.x)); o.y = f2bf(gelu_f(s.y)*b2f(v0.y));
    o.z = f2bf(gelu_f(s.z)*b2f(v1.x)); o.w = f2bf(gelu_f(s.w)*b2f(v1.y));
    *(ushort4*)(hg + (size_t)pix*HGLD + f) = o;
  } else {
    float r[2];
    #pragma unroll
    for (int c=0;c<2;c++){
      int ff = 680 + c;
      float s = dwb[ff];
      #pragma unroll
      for (int l=0;l<9;l++){
        int yy = y + l/3 - 1, xx = x + l%3 - 1;
        if (yy>=0 && yy<HH && xx>=0 && xx<WW)
          s += b2f(hb[(size_t)(yy*WW+xx)*1364 + ff]) * dwwT[(size_t)l*684 + ff];
      }
      r[c] = gelu_f(s) * b2f(hsrc[(size_t)pix*1364 + HF_ + ff]);
    }
    // write 680,681 + zero the pad cols 682..687 (fc2 staging reads through lda=688)
    ushort4 o1; o1.x = f2bf(r[0]); o1.y = f2bf(r[1]); o1.z = 0; o1.w = 0;
    ushort4 o2 = {0,0,0,0};
    *(ushort4*)(hg + (size_t)pix*HGLD + 680) = o1;
    *(ushort4*)(hg + (size_t)pix*HGLD + 684) = o2;
  }
}

extern "C" void kernel_launch(void* const* d_in, const int* in_sizes, int n_in,
                              void* d_out, int out_size, void* d_ws, size_t ws_size,
                              hipStream_t stream) {
  const float* x    = (const float*)d_in[0];
  const float* rct  = (const float*)d_in[1];
  const float* sls  = (const float*)d_in[2];
  const float* n1w  = (const float*)d_in[3];
  const float* n1b  = (const float*)d_in[4];
  const float* q_w  = (const float*)d_in[5];
  const float* q_b  = (const float*)d_in[6];
  const float* kv_w = (const float*)d_in[7];
  const float* kv_b = (const float*)d_in[8];
  const float* temp = (const float*)d_in[9];
  const float* qe   = (const float*)d_in[10];
  const float* rpb  = (const float*)d_in[11];
  const float* lt   = (const float*)d_in[12];
  const float* lb   = (const float*)d_in[13];
  const float* sr_w = (const float*)d_in[14];
  const float* sr_b = (const float*)d_in[15];
  const float* npw  = (const float*)d_in[16];
  const float* npb  = (const float*)d_in[17];
  const float* c1w  = (const float*)d_in[18];
  const float* c1b  = (const float*)d_in[19];
  const float* c2w  = (const float*)d_in[20];
  const float* c2b  = (const float*)d_in[21];
  const float* pw   = (const float*)d_in[22];
  const float* pb   = (const float*)d_in[23];
  const float* n2w  = (const float*)d_in[24];
  const float* n2b  = (const float*)d_in[25];
  const float* f1w  = (const float*)d_in[26];
  const float* f1b  = (const float*)d_in[27];
  const float* dww  = (const float*)d_in[28];
  const float* dwb  = (const float*)d_in[29];
  const float* f2w  = (const float*)d_in[30];
  const float* f2bb = (const float*)d_in[31];
  const int*  ridx  = (const int*)d_in[32];
  float* outp = (float*)d_out;

  char* ws = (char*)d_ws;
  // bf16 activation pipeline; all offsets 256-B aligned
  constexpr size_t SZ_BNC2 = (size_t)MROWS*C_*2;        // 12,845,056
  constexpr size_t SZ_KV2  = (size_t)MROWS*512*2;       // 25,690,112
  constexpr size_t SZ_ATTN = (size_t)B_*NH_*N_*58*4;    // 46,563,328
  size_t o_xn   = 0;                                    // xn/xn2 bf16 (dead after 17)
  size_t o_qn   = o_xn   + SZ_BNC2;                     // q/qn bf16 (dead after 10b)
  size_t o_qs   = o_qn   + SZ_BNC2;                     // qsc bf16 (dead after 12)
  size_t o_kv   = o_qs   + SZ_BNC2;                     // kv bf16 (dead after 14)
  size_t o_attn = o_kv   + SZ_KV2;                      // attn f32 (dead after 14)
  size_t o_xsr  = o_attn + SZ_ATTN;                     // xsr bf16 (dead after 7)
  size_t o_xpln = o_xsr  + SZ_BNC2;
  size_t o_kvp2 = o_xpln + (size_t)B_*PL_*C_*2;
  size_t o_cpb  = o_kvp2 + (size_t)B_*PL_*512*2;
  size_t o_outb = o_cpb  + (size_t)1024*8*4;
  size_t o_x2   = o_outb + SZ_BNC2;
  size_t o_qlt  = o_x2   + (size_t)MROWS*C_*4;
  size_t o_wq   = o_qlt  + (size_t)MROWS*72*4;
  size_t o_wkv  = o_wq   + (size_t)65536*2;
  size_t o_wsr  = o_wkv  + (size_t)131072*2;
  size_t o_wp   = o_wsr  + (size_t)65536*2;
  size_t o_wf1  = o_wp   + (size_t)65536*2;
  size_t o_wf2  = o_wf1  + (size_t)349184*2;
  size_t o_w72  = o_wf2  + (size_t)256*F2LD*2;
  size_t o_dwwT = o_w72  + (size_t)72*256*2;            // end ~164 MB
  size_t o_h    = o_kv;   // hbuf bf16 68.4MB over kv+attn (dead after 14); ends < o_xsr
  size_t o_hg   = 0;      // hg bf16 34.5MB over xn+qn+qs (all dead by 18); ends < o_kv

  u16*   xn   = (u16*)(ws + o_xn);
  u16*   qbuf = (u16*)(ws + o_qn);
  u16*   qsc  = (u16*)(ws + o_qs);
  u16*   kv   = (u16*)(ws + o_kv);
  float* attn = (float*)(ws + o_attn);
  u16*   xsr  = (u16*)(ws + o_xsr);
  u16*   xpln = (u16*)(ws + o_xpln);
  u16*   kvp2 = (u16*)(ws + o_kvp2);
  float* cpb  = (float*)(ws + o_cpb);
  u16*   outb = (u16*)(ws + o_outb);
  float* x2   = (float*)(ws + o_x2);
  float* qlt  = (float*)(ws + o_qlt);
  u16*   wq   = (u16*)(ws + o_wq);
  u16*   wkv  = (u16*)(ws + o_wkv);
  u16*   wsr  = (u16*)(ws + o_wsr);
  u16*   wp   = (u16*)(ws + o_wp);
  u16*   wf1  = (u16*)(ws + o_wf1);
  u16*   wf2  = (u16*)(ws + o_wf2);
  u16*   w72  = (u16*)(ws + o_w72);
  float* dwwT = (float*)(ws + o_dwwT);
  u16*   hbuf = (u16*)(ws + o_h);
  u16*   hg   = (u16*)(ws + o_hg);

  // 0. weight conversions (bf16 copies)
  cvt4_kernel<<<(65536/4+255)/256, 256, 0, stream>>>(q_w,  wq,  65536/4);
  cvt4_kernel<<<(131072/4+255)/256,256, 0, stream>>>(kv_w, wkv, 131072/4);
  cvt4_kernel<<<(65536/4+255)/256, 256, 0, stream>>>(sr_w, wsr, 65536/4);
  cvt4_kernel<<<(65536/4+255)/256, 256, 0, stream>>>(pw,   wp,  65536/4);
  cvt4_kernel<<<(349184/4+255)/256,256, 0, stream>>>(f1w,  wf1, 349184/4);
  cvt_pad_kernel<<<(256*F2LD+255)/256, 256, 0, stream>>>(f2w, wf2, 256, HF_, F2LD);
  build_w72<<<72, 256, 0, stream>>>(lt, w72);
  build_dwwT<<<9, 256, 0, stream>>>(dww, dwwT);

  // 1. xn = LN(x) -> bf16
  ln_kernel<<<MROWS, 256, 0, stream>>>(x, n1w, n1b, xn);
  // 2. q = xn @ q_w^T + q_b -> bf16
  gemm64b<0,0,1><<<dim3(392,4), 256, 0, stream>>>(xn, C_, wq, C_, q_b, nullptr, qbuf, MROWS, 256, 256);
  // 3. kv = xn @ kv_w^T + kv_b -> bf16
  gemm64b<0,0,1><<<dim3(392,8), 256, 0, stream>>>(xn, C_, wkv, C_, kv_b, nullptr, kv, MROWS, 512, 256);
  // 4. q_norm (in place) + q_scaled
  qpost_kernel<<<MROWS, 256, 0, stream>>>(qbuf, qe, temp, sls, qsc);
  // 5. k l2norm in place
  knorm_kernel<<<MROWS, 256, 0, stream>>>(kv);
  // 6. x_sr = gelu(xn @ sr_w^T + sr_b) -> bf16
  gemm64b<1,0,1><<<dim3(392,4), 256, 0, stream>>>(xn, C_, wsr, C_, sr_b, nullptr, xsr, MROWS, 256, 256);
  // 7. 8x8 avg pool + LN(normp) -> bf16
  pool_ln_kernel<<<B_*PL_, 256, 0, stream>>>(xsr, npw, npb, xpln);
  // 8. kvp2 = xpln @ kv_w^T + kv_b -> bf16
  gemm64b<0,0,1><<<dim3(7,8), 256, 0, stream>>>(xpln, C_, wkv, C_, kv_b, nullptr, kvp2, B_*PL_, 512, 256);
  // 9. k_pool l2norm in place
  knorm_kernel<<<B_*PL_, 256, 0, stream>>>(kvp2);
  // 10. CPB MLP
  cpb_kernel<<<1024, 256, 0, stream>>>(rct, c1w, c1b, c2w, c2b, cpb);
  // 10b. qlt = qn @ w72^T + lb -> f32
  gemm64b<0,0,0><<<dim3(392,2), 256, 0, stream>>>(qbuf, C_, w72, C_, lb, nullptr, qlt, MROWS, 72, 256);
  // 11. local attention logits
  attn_local_kernel<<<MROWS, 256, 0, stream>>>(qsc, kv, rpb, attn);
  // 12. pooled attention logits (MFMA, bf16 direct)
  attn_pool_mfma<<<dim3(49,64), 256, 0, stream>>>(qsc, kvp2, cpb, ridx, attn);
  // 13. softmax over 58
  softmax_kernel<<<(B_*NH_*N_)/4, 256, 0, stream>>>(attn);
  // 14. x_local + x_pool -> outb bf16
  xout_v2<<<MROWS, 256, 0, stream>>>(qlt, attn, kv, kvp2, outb);
  // 15. x2 = x + outb @ proj_w^T + proj_b -> f32
  gemm64b<0,1,0><<<dim3(392,4), 256, 0, stream>>>(outb, C_, wp, C_, pb, x, x2, MROWS, 256, 256);
  // 16. xn2 = LN(x2) -> bf16 (reuses xn)
  ln_kernel<<<MROWS, 256, 0, stream>>>(x2, n2w, n2b, xn);
  // 17. h = xn2 @ fc1_w^T + fc1_b -> bf16
  gemm128b<0,0,1><<<dim3(196,11), 256, 0, stream>>>(xn, C_, wf1, C_, f1b, nullptr, hbuf, MROWS, 1364, 256);
  // 18. hg = gelu(dwconv(h1)+dwb) * v -> bf16 (stride HGLD, pads zeroed)
  dwconv_v2<<<(MROWS*171+255)/256, 256, 0, stream>>>(hbuf, dwwT, dwb, hg);
  // 19. out = x2 + hg @ fc2_w^T + fc2_b -> f32
  gemm64b<0,1,0><<<dim3(392,4), 256, 0, stream>>>(hg, HGLD, wf2, F2LD, f2bb, x2, outp, MROWS, 256, HF_);
}